// Round 12
// baseline (528.775 us; speedup 1.0000x reference)
//
#include <hip/hip_runtime.h>
#include <hip/hip_bf16.h>

#define BB 8
#define NN 2048
#define FIN 512
#define FOUT 256
#define EE 5
#define ALPHA_ 0.2f
#define NEGV -9e15f
#define JW 512   // j-window per jz

typedef __hip_bfloat16 bf16;
typedef __bf16 bf16x8 __attribute__((ext_vector_type(8)));
typedef float f32x4 __attribute__((ext_vector_type(4)));
typedef unsigned long long u64;

__device__ __forceinline__ float bf2f(bf16 x) { return __bfloat162float(x); }
__device__ __forceinline__ bf16 f2bf(float x) { return __float2bfloat16(x); }

// async global->LDS, 16B per lane. LDS dest must be wave-uniform base + lane*16
// (true for all call sites: lds offset == idx*16B with idx = tid + i*256).
__device__ __forceinline__ void async16(const bf16* g, bf16* l) {
    __builtin_amdgcn_global_load_lds(
        (const __attribute__((address_space(1))) void*)g,
        (__attribute__((address_space(3))) void*)l, 16, 0, 0);
}

// LDS tile swizzle (both-sides transform, rule #21): tiles are [row][32] bf16 =
// row stride 64B; fragment reads at row*64 + quad*16 are an 8-way bank conflict.
// Permute the four 16B segments per row by seg ^= (row>>1)&3 on BOTH the global
// source (staging) and the LDS read offset. 8-way -> 2-way (free). Verified r3:
// SQ_LDS_BANK_CONFLICT = 0.
//
// Pipelined GEMM schedule (proven r0->r3/r8/r11): double-buffered LDS, prefetch
// before wait, counted s_waitcnt vmcnt(N) (never 0 mid-loop) + raw s_barrier,
// setprio(1) around MFMA. Buffer parity COMPILE-TIME (r5 lesson). Pipeline
// depth LOCKED at 1: r9's depth-3 halved occupancy and cost +59% (TLP-bound).

// ---------------- fused: split fp32->bf16 hi/lo (row-major) + bf16 transpose ----
// Replaces split_f32_bf16 + the featT transpose: feat (67MB) is read ONCE.
__global__ void split_transpose(const float* __restrict__ in,
                                bf16* __restrict__ hi, bf16* __restrict__ lo,
                                bf16* __restrict__ outT) {
    __shared__ bf16 tile[32][33];
    long bi = (long)blockIdx.z * NN * FIN;   // feat / fh / fl base
    long bo = (long)blockIdx.z * FIN * NN;   // featT base
    int c0 = blockIdx.x * 32, r0 = blockIdx.y * 32;  // c = f, r = n
    int x = threadIdx.x, y = threadIdx.y;            // 32 x 8
    for (int k = 0; k < 4; k++) {
        int r = y + k * 8;
        long idx = bi + (long)(r0 + r) * FIN + c0 + x;
        float f = in[idx];
        bf16 h = f2bf(f);
        hi[idx] = h;
        lo[idx] = f2bf(f - bf2f(h));
        tile[r][x] = h;
    }
    __syncthreads();
    for (int k = 0; k < 4; k++) {
        int r = y + k * 8;
        outT[bo + (long)(c0 + r) * NN + r0 + x] = tile[x][r];
    }
}

// ---------------- pack adj (int32 > 0) into 64-col bitmasks ----------------
__global__ void pack_adj(const int* __restrict__ adj, u64* __restrict__ adjm) {
    long wid = (((long)blockIdx.x * 256) + threadIdx.x) >> 6;
    int lane = threadIdx.x & 63;
    long base = wid * 256;
    for (int c = 0; c < 4; c++) {
        int a = adj[base + c * 64 + lane];
        u64 m = __ballot(a > 0);
        if (lane == 0) adjm[base / 64 + c] = m;
    }
}

// ---------------- transpose+split: fp32 [R,C] -> bf16 hi/lo [C,R] ----------------
__global__ void transpose_split(const float* __restrict__ in,
                                bf16* __restrict__ hi, bf16* __restrict__ lo,
                                int R, int C) {
    __shared__ bf16 th[32][33], tl[32][33];
    int c0 = blockIdx.x * 32, r0 = blockIdx.y * 32;
    int x = threadIdx.x, y = threadIdx.y;  // 32 x 8
    for (int k = 0; k < 4; k++) {
        int r = y + k * 8;
        float f = in[(long)(r0 + r) * C + c0 + x];
        bf16 h = f2bf(f);
        th[r][x] = h;
        tl[r][x] = f2bf(f - bf2f(h));
    }
    __syncthreads();
    for (int k = 0; k < 4; k++) {
        int r = y + k * 8;
        hi[(long)(c0 + r) * R + r0 + x] = th[x][r];
        lo[(long)(c0 + r) * R + r0 + x] = tl[x][r];
    }
}

// ---------------- transpose + convert: fp32 [R,C] -> bf16 [C,R] ----------------
__global__ void transpose_f32_bf16(const float* __restrict__ in, bf16* __restrict__ out,
                                   int R, int C, long sin_b, long sout_b) {
    __shared__ bf16 tile[32][33];
    long bi = (long)blockIdx.z * sin_b;
    long bo = (long)blockIdx.z * sout_b;
    int c0 = blockIdx.x * 32, r0 = blockIdx.y * 32;
    int x = threadIdx.x, y = threadIdx.y;
    for (int k = 0; k < 4; k++) {
        int r = y + k * 8;
        tile[r][x] = f2bf(in[bi + (long)(r0 + r) * C + c0 + x]);
    }
    __syncthreads();
    for (int k = 0; k < 4; k++) {
        int r = y + k * 8;
        out[bo + (long)(c0 + r) * R + r0 + x] = tile[x][r];
    }
}

// ---------------- split GEMM: C = (Ah+Al)[M,K] @ (Bh+Bl)[N,K]^T + bias ----------------
// Pipelined. 8 loads/step -> steady vmcnt(8), final vmcnt(0).
__global__ __launch_bounds__(256) void gemm_bt_split(
        const bf16* __restrict__ Ah, const bf16* __restrict__ Al,
        const bf16* __restrict__ Bh, const bf16* __restrict__ Bl,
        bf16* __restrict__ Chi, bf16* __restrict__ Clo,
        const float* __restrict__ bias, int Nn, int K) {
    __shared__ alignas(16) bf16 Ash[2][128 * 32], Asl[2][128 * 32];
    __shared__ alignas(16) bf16 Bsh[2][128 * 32], Bsl[2][128 * 32];
    int tid = threadIdx.x;
    int lane = tid & 63, ww = tid >> 6;
    int wm = ww >> 1, wn = ww & 1;
    int quad = lane >> 4, l16 = lane & 15;
    int qx = quad ^ ((l16 >> 1) & 3);            // swizzled read segment
    int sseg = (tid & 3) ^ ((tid >> 3) & 3);     // swizzled source segment (staging)
    int m0 = blockIdx.x * 128, n0 = blockIdx.y * 128;
    f32x4 acc[4][4] = {};
    auto STAGE = [&](int k0, int buf) {
#pragma unroll
        for (int i = 0; i < 2; i++) {
            int idx = tid + i * 256;
            int row = idx >> 2;
            long ao = (long)(m0 + row) * K + k0 + sseg * 8;
            long bo = (long)(n0 + row) * K + k0 + sseg * 8;
            async16(&Ah[ao], &Ash[buf][idx * 8]);
            async16(&Al[ao], &Asl[buf][idx * 8]);
            async16(&Bh[bo], &Bsh[buf][idx * 8]);
            async16(&Bl[bo], &Bsl[buf][idx * 8]);
        }
    };
    int nk = K / 32;   // even for all call sites (16 or 8)
    STAGE(0, 0);
    for (int s = 0; s < nk; s += 2) {
#pragma unroll
        for (int u = 0; u < 2; u++) {            // compile-time buffer parity
            int step = s + u;
            if (step + 1 < nk) STAGE((step + 1) * 32, u ^ 1);
            if (step + 1 < nk) asm volatile("s_waitcnt vmcnt(8)" ::: "memory");
            else               asm volatile("s_waitcnt vmcnt(0)" ::: "memory");
            __builtin_amdgcn_s_barrier();
            __builtin_amdgcn_sched_barrier(0);
            __builtin_amdgcn_s_setprio(1);
            bf16x8 afh[4], afl[4], bfh[4], bfl[4];
#pragma unroll
            for (int mi = 0; mi < 4; mi++) {
                int so = (wm * 64 + mi * 16 + l16) * 32 + qx * 8;
                afh[mi] = *(const bf16x8*)(&Ash[u][so]);
                afl[mi] = *(const bf16x8*)(&Asl[u][so]);
            }
#pragma unroll
            for (int ni = 0; ni < 4; ni++) {
                int so = (wn * 64 + ni * 16 + l16) * 32 + qx * 8;
                bfh[ni] = *(const bf16x8*)(&Bsh[u][so]);
                bfl[ni] = *(const bf16x8*)(&Bsl[u][so]);
            }
#pragma unroll
            for (int mi = 0; mi < 4; mi++)
#pragma unroll
                for (int ni = 0; ni < 4; ni++) {
                    acc[mi][ni] = __builtin_amdgcn_mfma_f32_16x16x32_bf16(afh[mi], bfh[ni], acc[mi][ni], 0, 0, 0);
                    acc[mi][ni] = __builtin_amdgcn_mfma_f32_16x16x32_bf16(afh[mi], bfl[ni], acc[mi][ni], 0, 0, 0);
                    acc[mi][ni] = __builtin_amdgcn_mfma_f32_16x16x32_bf16(afl[mi], bfh[ni], acc[mi][ni], 0, 0, 0);
                }
            __builtin_amdgcn_s_setprio(0);
            __builtin_amdgcn_sched_barrier(0);
            __builtin_amdgcn_s_barrier();        // readers done before buf[u] restaged
            __builtin_amdgcn_sched_barrier(0);
        }
    }
    for (int mi = 0; mi < 4; mi++)
        for (int ni = 0; ni < 4; ni++) {
            int col = n0 + wn * 64 + ni * 16 + l16;
            float bv = bias ? bias[col] : 0.f;
            for (int r = 0; r < 4; r++) {
                int row = m0 + wm * 64 + mi * 16 + quad * 4 + r;
                float v = acc[mi][ni][r] + bv;
                bf16 h = f2bf(v);
                Chi[(long)row * Nn + col] = h;
                Clo[(long)row * Nn + col] = f2bf(v - bf2f(h));
            }
        }
}

// ---------------- plain bf16 GEMM: C[M,N] = A[M,K] @ Bt[N,K]^T (pipelined) -----
__global__ __launch_bounds__(256) void gemm_bt(
        const bf16* __restrict__ A, const bf16* __restrict__ Bt,
        bf16* __restrict__ C, int Nn, int K, long sA, long sB, long sC) {
    __shared__ alignas(16) bf16 As[2][128 * 32];
    __shared__ alignas(16) bf16 Bs[2][128 * 32];
    const bf16* Ab = A + (long)blockIdx.z * sA;
    const bf16* Bb = Bt + (long)blockIdx.z * sB;
    bf16* Cb = C + (long)blockIdx.z * sC;
    int tid = threadIdx.x;
    int lane = tid & 63, ww = tid >> 6;
    int wm = ww >> 1, wn = ww & 1;
    int quad = lane >> 4, l16 = lane & 15;
    int qx = quad ^ ((l16 >> 1) & 3);
    int sseg = (tid & 3) ^ ((tid >> 3) & 3);
    int m0 = blockIdx.x * 128, n0 = blockIdx.y * 128;
    f32x4 acc[4][4] = {};
    auto STAGE = [&](int k0, int buf) {
#pragma unroll
        for (int i = 0; i < 2; i++) {
            int idx = tid + i * 256;
            int row = idx >> 2;
            async16(&Ab[(long)(m0 + row) * K + k0 + sseg * 8], &As[buf][idx * 8]);
            async16(&Bb[(long)(n0 + row) * K + k0 + sseg * 8], &Bs[buf][idx * 8]);
        }
    };
    int nk = K / 32;   // even for all call sites
    STAGE(0, 0);
    for (int s = 0; s < nk; s += 2) {
#pragma unroll
        for (int u = 0; u < 2; u++) {
            int step = s + u;
            if (step + 1 < nk) STAGE((step + 1) * 32, u ^ 1);
            if (step + 1 < nk) asm volatile("s_waitcnt vmcnt(4)" ::: "memory");
            else               asm volatile("s_waitcnt vmcnt(0)" ::: "memory");
            __builtin_amdgcn_s_barrier();
            __builtin_amdgcn_sched_barrier(0);
            __builtin_amdgcn_s_setprio(1);
            bf16x8 af[4], bfr[4];
#pragma unroll
            for (int mi = 0; mi < 4; mi++)
                af[mi] = *(const bf16x8*)(&As[u][(wm * 64 + mi * 16 + l16) * 32 + qx * 8]);
#pragma unroll
            for (int ni = 0; ni < 4; ni++)
                bfr[ni] = *(const bf16x8*)(&Bs[u][(wn * 64 + ni * 16 + l16) * 32 + qx * 8]);
#pragma unroll
            for (int mi = 0; mi < 4; mi++)
#pragma unroll
                for (int ni = 0; ni < 4; ni++)
                    acc[mi][ni] = __builtin_amdgcn_mfma_f32_16x16x32_bf16(
                        af[mi], bfr[ni], acc[mi][ni], 0, 0, 0);
            __builtin_amdgcn_s_setprio(0);
            __builtin_amdgcn_sched_barrier(0);
            __builtin_amdgcn_s_barrier();
            __builtin_amdgcn_sched_barrier(0);
        }
    }
    for (int mi = 0; mi < 4; mi++)
        for (int ni = 0; ni < 4; ni++) {
            int col = n0 + wn * 64 + ni * 16 + l16;
            for (int r = 0; r < 4; r++) {
                int row = m0 + wm * 64 + mi * 16 + quad * 4 + r;
                Cb[(long)row * Nn + col] = f2bf(acc[mi][ni][r]);
            }
        }
}

// ---------------- PV GEMM with fused per-chunk softmax rescale (FA-style) -----
// Pipelined like gemm_bt. XCD-aware block swizzle (T1): 1-D grid of 512; the 4
// n-blocks sharing one P m-panel map to consecutive slots on the SAME XCD.
__global__ __launch_bounds__(256) void gemm_pv(
        const bf16* __restrict__ A, const bf16* __restrict__ Bt,
        bf16* __restrict__ C, const float* __restrict__ rs,
        const float* __restrict__ fin) {
    __shared__ alignas(16) bf16 As[2][128 * 32];
    __shared__ alignas(16) bf16 Bs[2][128 * 32];
    int flat = blockIdx.x;                 // [0,512)
    int xcd = flat & 7, j = flat >> 3;     // round-robin XCD assumption
    int panel = xcd * 16 + (j >> 2);       // [0,128) = (b,m) panel
    int b = panel >> 4;
    int m0 = (panel & 15) * 128;
    int n0 = (j & 3) * 128;
    const bf16* Ab = A + (long)b * NN * NN;
    const bf16* Bb = Bt + (long)b * FIN * NN;
    bf16* Cb = C + (long)b * NN * FIN;
    int tid = threadIdx.x;
    int lane = tid & 63, ww = tid >> 6;
    int wm = ww >> 1, wn = ww & 1;
    int quad = lane >> 4, l16 = lane & 15;
    int qx = quad ^ ((l16 >> 1) & 3);
    int sseg = (tid & 3) ^ ((tid >> 3) & 3);
    f32x4 acc[4][4] = {};
    auto STAGE = [&](int k0, int buf) {
#pragma unroll
        for (int i = 0; i < 2; i++) {
            int idx = tid + i * 256;
            int row = idx >> 2;
            async16(&Ab[(long)(m0 + row) * NN + k0 + sseg * 8], &As[buf][idx * 8]);
            async16(&Bb[(long)(n0 + row) * NN + k0 + sseg * 8], &Bs[buf][idx * 8]);
        }
    };
    const int nk = NN / 32;  // 64
    STAGE(0, 0);
    for (int s = 0; s < nk; s += 2) {
#pragma unroll
        for (int u = 0; u < 2; u++) {
            int step = s + u;
            int k0 = step * 32;
            if (k0 && !(k0 & 127)) {          // entering chunk c: rescale acc
                int c = k0 >> 7;
#pragma unroll
                for (int mi = 0; mi < 4; mi++) {
                    float4 rv = *(const float4*)(&rs[((long)b * 16 + c) * NN
                                                     + m0 + wm * 64 + mi * 16 + quad * 4]);
#pragma unroll
                    for (int ni = 0; ni < 4; ni++) {
                        acc[mi][ni][0] *= rv.x;
                        acc[mi][ni][1] *= rv.y;
                        acc[mi][ni][2] *= rv.z;
                        acc[mi][ni][3] *= rv.w;
                    }
                }
            }
            if (step + 1 < nk) STAGE((step + 1) * 32, u ^ 1);
            if (step + 1 < nk) asm volatile("s_waitcnt vmcnt(4)" ::: "memory");
            else               asm volatile("s_waitcnt vmcnt(0)" ::: "memory");
            __builtin_amdgcn_s_barrier();
            __builtin_amdgcn_sched_barrier(0);
            __builtin_amdgcn_s_setprio(1);
            bf16x8 af[4], bfr[4];
#pragma unroll
            for (int mi = 0; mi < 4; mi++)
                af[mi] = *(const bf16x8*)(&As[u][(wm * 64 + mi * 16 + l16) * 32 + qx * 8]);
#pragma unroll
            for (int ni = 0; ni < 4; ni++)
                bfr[ni] = *(const bf16x8*)(&Bs[u][(wn * 64 + ni * 16 + l16) * 32 + qx * 8]);
#pragma unroll
            for (int mi = 0; mi < 4; mi++)
#pragma unroll
                for (int ni = 0; ni < 4; ni++)
                    acc[mi][ni] = __builtin_amdgcn_mfma_f32_16x16x32_bf16(
                        af[mi], bfr[ni], acc[mi][ni], 0, 0, 0);
            __builtin_amdgcn_s_setprio(0);
            __builtin_amdgcn_sched_barrier(0);
            __builtin_amdgcn_s_barrier();
            __builtin_amdgcn_sched_barrier(0);
        }
    }
    for (int mi = 0; mi < 4; mi++) {
        float4 fv = *(const float4*)(&fin[(long)b * NN + m0 + wm * 64 + mi * 16 + quad * 4]);
        for (int ni = 0; ni < 4; ni++) {
            int col = n0 + wn * 64 + ni * 16 + l16;
            float fvr[4] = { fv.x, fv.y, fv.z, fv.w };
            for (int r = 0; r < 4; r++) {
                int row = m0 + wm * 64 + mi * 16 + quad * 4 + r;
                Cb[(long)row * FIN + col] = f2bf(acc[mi][ni][r] * fvr[r]);
            }
        }
    }
}

// ---------------- Ay[b,n] = (hh+hl)[b,n,:] . a2 ----------------
__global__ void ay_kernel(const bf16* __restrict__ hh, const bf16* __restrict__ hl,
                          const float* __restrict__ a2, float* __restrict__ Ay) {
    int lane = threadIdx.x & 63, w = threadIdx.x >> 6;
    long row = (long)blockIdx.x * 4 + w;
    float p = 0.f;
    for (int i = 0; i < 4; i++) {
        int d = i * 64 + lane;
        p += (bf2f(hh[row * FOUT + d]) + bf2f(hl[row * FOUT + d])) * a2[d];
    }
    for (int off = 32; off; off >>= 1) p += __shfl_xor(p, off);
    if (lane == 0) Ay[row] = p;
}

// ---------------- single score pass: stats + unnormalized P~ (all 8 batches) ----------------
// r8-verbatim body (proven best: 92.7-93.6us, VGPR 120, FETCH 78MB, conflicts 0)
// + r12 change: XCD window co-location. Grid = 1024 blocks = exactly 256CU x
// 4blk/CU, all co-resident; dispatch round-robins flat%8 over XCDs. Remap so
// each XCD owns 4 complete (b,jz) H-windows (32 i-blocks each): the 512KB
// window is then pulled into that XCD's L2 once and all 32 blocks hit L2
// (~200cy) instead of L3 (~2-3x) -- this kernel is cache-hit-LATENCY bound
// (HBM only 20%, utils ~22-25%). Bijective: flat <-> (xcd, widx, iblk).
// Schedule arc CLOSED: depth-1/2-buffer optimal (M_rep=2 r4/r7, 1-barrier r5,
// depth-3 r9 all refuted).
__global__ __launch_bounds__(256) void pass_score(
        const bf16* __restrict__ qh_, const bf16* __restrict__ ql_,
        const bf16* __restrict__ hh_, const bf16* __restrict__ hl_,
        const u64* __restrict__ adjm, const float* __restrict__ Ay,
        float* __restrict__ mpm, float* __restrict__ mpl,
        bf16* __restrict__ P) {
    __shared__ alignas(16) bf16 Hsh[2][128 * 32], Hsl[2][128 * 32];
    __shared__ alignas(16) bf16 pst[4][16 * 64];   // per-wave 16x64 half-tile, swizzled
    int tid = threadIdx.x;
    int lane = tid & 63, w = tid >> 6;
    int quad = lane >> 4, l16 = lane & 15;
    int qx = quad ^ ((l16 >> 1) & 3);            // swizzled read segment
    int sseg = (tid & 3) ^ ((tid >> 3) & 3);     // swizzled source segment (staging)
    // XCD window co-location: flat -> (xcd, widx, iblk) -> (b, jz, i0)
    int flat = blockIdx.x;                 // [0,1024)
    int xcd = flat & 7, slot = flat >> 3;  // slot in [0,128)
    int widx = slot >> 5, iblk = slot & 31;
    int window = widx * 8 + xcd;           // [0,32)
    int b = window >> 2, jz = window & 3;
    int i0 = iblk * 64 + w * 16;
    long qoff = ((long)b * NN + i0) * FOUT;
    const bf16* hbh = hh_ + ((long)b * NN + (long)jz * JW) * FOUT;
    const bf16* hbl = hl_ + ((long)b * NN + (long)jz * JW) * FOUT;
    const u64* amb = adjm + ((long)b * NN + i0) * (NN / 64) + jz * (JW / 64);
    bf16* pw = pst[w];

    bf16x8 qfh[8], qfl[8];
#pragma unroll
    for (int kk = 0; kk < 8; kk++) {
        qfh[kk] = *(const bf16x8*)(&qh_[qoff + (long)l16 * FOUT + kk * 32 + quad * 8]);
        qfl[kk] = *(const bf16x8*)(&ql_[qoff + (long)l16 * FOUT + kk * 32 + quad * 8]);
    }
    float ay_[4];
#pragma unroll
    for (int r = 0; r < 4; r++) ay_[r] = Ay[(long)b * NN + i0 + quad * 4 + r];

    float m_[4], l_[4];
#pragma unroll
    for (int r = 0; r < 4; r++) { m_[r] = -3.0e38f; l_[r] = 0.f; }

    // stage (jc,kk) into buffer `buf`: 4 global_load_lds/thread (source-swizzled)
    auto STAGE = [&](int jc, int kk, int buf) {
#pragma unroll
        for (int i = 0; i < 2; i++) {
            int idx = tid + i * 256;
            int row = idx >> 2;
            long go = (long)(jc * 128 + row) * FOUT + kk * 32 + sseg * 8;
            async16(&hbh[go], &Hsh[buf][idx * 8]);
            async16(&hbl[go], &Hsl[buf][idx * 8]);
        }
    };

    f32x4 sacc[8];
#pragma unroll
    for (int ni = 0; ni < 8; ni++) sacc[ni] = (f32x4){0.f, 0.f, 0.f, 0.f};

    STAGE(0, 0, 0);
    for (int jc = 0; jc < 4; jc++) {          // runtime loop (uniform)
#pragma unroll
        for (int kk = 0; kk < 8; kk++) {      // compile-time: qfh[kk] stays in VGPRs
            const int cur = kk & 1;           // jc*8 is even -> buf parity = kk&1
            // prefetch next step into the other buffer
            if (kk < 7)           STAGE(jc, kk + 1, cur ^ 1);
            else if (jc < 3)      STAGE(jc + 1, 0, cur ^ 1);
            // wait until STAGE(jc,kk) landed; keep newest prefetch in flight
            if (kk == 0) {
                if (jc == 0) asm volatile("s_waitcnt vmcnt(4)" ::: "memory");
                else         asm volatile("s_waitcnt vmcnt(8)" ::: "memory");
            } else if (kk == 7 && jc == 3) {
                asm volatile("s_waitcnt vmcnt(0)" ::: "memory");
            } else {
                asm volatile("s_waitcnt vmcnt(4)" ::: "memory");
            }
            __builtin_amdgcn_s_barrier();     // buf[cur] staged for all waves
            __builtin_amdgcn_sched_barrier(0);

            __builtin_amdgcn_s_setprio(1);
#pragma unroll
            for (int ni = 0; ni < 8; ni++) {
                int so = (ni * 16 + l16) * 32 + qx * 8;
                bf16x8 hfh = *(const bf16x8*)(&Hsh[cur][so]);
                bf16x8 hfl = *(const bf16x8*)(&Hsl[cur][so]);
                sacc[ni] = __builtin_amdgcn_mfma_f32_16x16x32_bf16(qfh[kk], hfh, sacc[ni], 0, 0, 0);
                sacc[ni] = __builtin_amdgcn_mfma_f32_16x16x32_bf16(qfh[kk], hfl, sacc[ni], 0, 0, 0);
                sacc[ni] = __builtin_amdgcn_mfma_f32_16x16x32_bf16(qfl[kk], hfh, sacc[ni], 0, 0, 0);
            }
            __builtin_amdgcn_s_setprio(0);

            if (kk == 7) {
                // ---- epilogue for this jc: mask + leaky relu + online softmax ----
                u64 am[4][2];
#pragma unroll
                for (int r = 0; r < 4; r++) {
                    am[r][0] = amb[(long)(quad * 4 + r) * (NN / 64) + jc * 2 + 0];
                    am[r][1] = amb[(long)(quad * 4 + r) * (NN / 64) + jc * 2 + 1];
                }
#pragma unroll
                for (int ni = 0; ni < 8; ni++)
#pragma unroll
                    for (int r = 0; r < 4; r++) {
                        float v = sacc[ni][r] + ay_[r];
                        v = v > 0.f ? v : ALPHA_ * v;
                        int bit = (int)((am[r][ni >> 2] >> ((ni * 16 + l16) & 63)) & 1);
                        sacc[ni][r] = bit ? v : NEGV;
                    }
#pragma unroll
                for (int r = 0; r < 4; r++) {
                    float mc = -3.0e38f;
#pragma unroll
                    for (int ni = 0; ni < 8; ni++) mc = fmaxf(mc, sacc[ni][r]);
                    for (int off = 8; off; off >>= 1) mc = fmaxf(mc, __shfl_xor(mc, off));
                    float mnew = fmaxf(m_[r], mc);
                    float scale = __expf(m_[r] - mnew);
                    float ps = 0.f;
#pragma unroll
                    for (int ni = 0; ni < 8; ni++) {
                        float p = __expf(sacc[ni][r] - mnew);
                        sacc[ni][r] = p;
                        ps += p;
                    }
                    for (int off = 8; off; off >>= 1) ps += __shfl_xor(ps, off);
                    l_[r] = l_[r] * scale + ps;
                    m_[r] = mnew;
                    if (l16 == 0)
                        mpm[(((long)b * 4 + jz) * 4 + jc) * NN + i0 + quad * 4 + r] = mnew;
                }
                // ---- P~ store via swizzled per-wave LDS half-tiles (2 rounds) ----
#pragma unroll
                for (int h = 0; h < 2; h++) {
#pragma unroll
                    for (int ni = 0; ni < 4; ni++)
#pragma unroll
                        for (int r = 0; r < 4; r++) {
                            int row = quad * 4 + r;
                            int byt = (row * 128 + (ni * 16 + l16) * 2) ^ ((row & 7) << 4);
                            *(bf16*)((char*)pw + byt) = f2bf(sacc[h * 4 + ni][r]);
                        }
#pragma unroll
                    for (int s2 = 0; s2 < 2; s2++) {
                        int cq = quad + s2 * 4;
                        int byt = (l16 * 128 + cq * 16) ^ ((l16 & 7) << 4);
                        uint4 v = *(const uint4*)((const char*)pw + byt);
                        *(uint4*)(&P[((long)b * NN + i0 + l16) * NN + (long)jz * JW
                                     + jc * 128 + h * 64 + cq * 8]) = v;
                    }
                }
#pragma unroll
                for (int ni = 0; ni < 8; ni++) sacc[ni] = (f32x4){0.f, 0.f, 0.f, 0.f};
            }
            __builtin_amdgcn_sched_barrier(0);
            __builtin_amdgcn_s_barrier();   // all waves done reading buf[cur] before restage
            __builtin_amdgcn_sched_barrier(0);
        }
    }
    if (l16 == 0)
#pragma unroll
        for (int r = 0; r < 4; r++)
            mpl[((long)b * 4 + jz) * NN + i0 + quad * 4 + r] = l_[r];
}

// ---------------- merge window stats -> chunk ratios rs + final scale fin ----------------
// rs[b,c,n] = exp(m_{c-1} - m_c)  (c=1..15; c=0 unused)
// fin[b,n]  = exp(m_15 - m_glob) / l_glob
__global__ void ml_merge(const float* __restrict__ mpm, const float* __restrict__ mpl,
                         float* __restrict__ rs, float* __restrict__ fin) {
    long row = (long)blockIdx.x * blockDim.x + threadIdx.x;  // [0, BB*NN)
    long b = row / NN, n = row % NN;
    float mc[16];
#pragma unroll
    for (int c = 0; c < 16; c++) mc[c] = mpm[(b * 16 + c) * NN + n];
    float m = fmaxf(fmaxf(mc[3], mc[7]), fmaxf(mc[11], mc[15]));
    float l = 0.f;
#pragma unroll
    for (int jz = 0; jz < 4; jz++)
        l += mpl[(b * 4 + jz) * NN + n] * __expf(mc[jz * 4 + 3] - m);
    fin[row] = __expf(mc[15] - m) / l;
#pragma unroll
    for (int c = 1; c < 16; c++)
        rs[(b * 16 + c) * NN + n] = __expf(mc[c - 1] - mc[c]);
}

// ---------------- e = X_bf16[*,512] @ W_f32[5,512]^T (fp32 out) ----------------
__global__ void e_kernel(const bf16* __restrict__ X, const float* __restrict__ Wt,
                         float* __restrict__ out) {
    int lane = threadIdx.x & 63, w = threadIdx.x >> 6;
    long row = (long)blockIdx.x * 4 + w;
    uint4 raw = *(const uint4*)(&X[row * FIN + lane * 8]);
    const bf16* xp = (const bf16*)&raw;
    float xv[8];
    for (int i = 0; i < 8; i++) xv[i] = bf2f(xp[i]);
    for (int e = 0; e < EE; e++) {
        float4 w0 = *(const float4*)(&Wt[e * FIN + lane * 8]);
        float4 w1 = *(const float4*)(&Wt[e * FIN + lane * 8 + 4]);
        float p = xv[0] * w0.x + xv[1] * w0.y + xv[2] * w0.z + xv[3] * w0.w
                + xv[4] * w1.x + xv[5] * w1.y + xv[6] * w1.z + xv[7] * w1.w;
        for (int off = 32; off; off >>= 1) p += __shfl_xor(p, off);
        if (lane == 0) out[row * EE + e] = p;
    }
}

// ---------------- out(fp32) = h1 + h2 + e1.Bw.e2 ----------------
__global__ void final_kernel(float* __restrict__ out,
                             const bf16* __restrict__ h1, const bf16* __restrict__ h2,
                             const float* __restrict__ e1, const float* __restrict__ e2,
                             const float* __restrict__ Bw) {
    long row = blockIdx.x;
    int o = threadIdx.x;
    float a[EE], c[EE];
    for (int i = 0; i < EE; i++) { a[i] = e1[row * EE + i]; c[i] = e2[row * EE + i]; }
    const float* bw = Bw + (long)o * EE * EE;
    float acc = 0.f;
    for (int i = 0; i < EE; i++)
        for (int j = 0; j < EE; j++)
            acc += bw[i * EE + j] * a[i] * c[j];
    long idx = row * FOUT + o;
    out[idx] = acc + bf2f(h1[idx]) + bf2f(h2[idx]);
}

extern "C" void kernel_launch(void* const* d_in, const int* in_sizes, int n_in,
                              void* d_out, int out_size, void* d_ws, size_t ws_size,
                              hipStream_t stream) {
    const float* feat = (const float*)d_in[0];
    const int*   adj  = (const int*)d_in[1];
    const float* W    = (const float*)d_in[2];
    const float* W1   = (const float*)d_in[3];
    const float* W2   = (const float*)d_in[4];
    const float* a1   = (const float*)d_in[5];
    const float* a2   = (const float*)d_in[6];
    const float* a12  = (const float*)d_in[7];
    const float* Lw   = (const float*)d_in[8];
    const float* Rw   = (const float*)d_in[9];
    const float* Bw   = (const float*)d_in[10];
    float* out = (float*)d_out;

    char* ws = (char*)d_ws;
    size_t off = 0;
    auto alloc = [&](size_t bytes) {
        char* p = ws + off;
        off += (bytes + 255) & ~(size_t)255;
        return p;
    };
    bf16* WTh  = (bf16*)alloc((size_t)FOUT * FIN * 2);
    bf16* WTl  = (bf16*)alloc((size_t)FOUT * FIN * 2);
    bf16* W1T  = (bf16*)alloc((size_t)FOUT * FIN * 2);
    bf16* W2T  = (bf16*)alloc((size_t)FOUT * FIN * 2);
    bf16* aTh  = (bf16*)alloc((size_t)FOUT * FOUT * 2);
    bf16* aTl  = (bf16*)alloc((size_t)FOUT * FOUT * 2);
    bf16* fh   = (bf16*)alloc((size_t)BB * NN * FIN * 2);     // 16.8 MB
    bf16* fl   = (bf16*)alloc((size_t)BB * NN * FIN * 2);     // 16.8 MB (fagg later)
    bf16* hh   = (bf16*)alloc((size_t)BB * NN * FOUT * 2);    // 8.4 MB (h1 later)
    bf16* hl   = (bf16*)alloc((size_t)BB * NN * FOUT * 2);    // 8.4 MB (h2 later)
    bf16* featT= (bf16*)alloc((size_t)BB * NN * FIN * 2);     // 16.8 MB
    float* Ay  = (float*)alloc((size_t)BB * NN * 4);
    float* mpm = (float*)alloc((size_t)BB * 4 * 4 * NN * 4);  // 1 MB
    float* mpl = (float*)alloc((size_t)BB * 4 * NN * 4);      // 256 KB
    float* rs  = (float*)alloc((size_t)BB * 16 * NN * 4);     // 2 MB chunk ratios
    float* fin = (float*)alloc((size_t)BB * NN * 4);          // 64 KB final scales
    float* e1  = (float*)alloc((size_t)BB * NN * EE * 4);
    float* e2  = (float*)alloc((size_t)BB * NN * EE * 4);
    u64* adjm  = (u64*)alloc((size_t)BB * NN * (NN / 64) * 8);// 4.2 MB
    bf16* P    = (bf16*)alloc((size_t)BB * NN * NN * 2);      // 67.1 MB (all batches)
    // aliases (lifetimes disjoint):  peak ws ~140 MB (ws is ~512 MB)
    bf16* qh   = (bf16*)d_out;                          // q pair in out (16.8 MB)
    bf16* ql   = qh + (size_t)BB * NN * FOUT;
    bf16* fagg = fl;                                    // fl dead after h-GEMM
    bf16* h1   = hh;                                    // h pair dead after scores
    bf16* h2   = hl;

    dim3 tb(32, 8, 1);
    // input conversions (feat read ONCE: split + featT transpose fused)
    split_transpose<<<dim3(FIN / 32, NN / 32, BB), tb, 0, stream>>>(feat, fh, fl, featT);
    pack_adj<<<(BB * NN * NN) / (256 * 4), 256, 0, stream>>>(adj, adjm);
    transpose_split<<<dim3(FOUT / 32, FIN / 32, 1), tb, 0, stream>>>(W, WTh, WTl, FIN, FOUT);
    transpose_split<<<dim3(FOUT / 32, FOUT / 32, 1), tb, 0, stream>>>(a12, aTh, aTl, FOUT, FOUT);
    transpose_f32_bf16<<<dim3(FOUT / 32, FIN / 32, 1), tb, 0, stream>>>(W1, W1T, FIN, FOUT, 0, 0);
    transpose_f32_bf16<<<dim3(FOUT / 32, FIN / 32, 1), tb, 0, stream>>>(W2, W2T, FIN, FOUT, 0, 0);
    // h = feat @ W   (split precision)
    gemm_bt_split<<<dim3(BB * NN / 128, FOUT / 128, 1), 256, 0, stream>>>(
        fh, fl, WTh, WTl, hh, hl, nullptr, FOUT, FIN);
    // Ay = h @ a2
    ay_kernel<<<BB * NN / 4, 256, 0, stream>>>(hh, hl, a2, Ay);
    // q = h @ a12 + a1   (folds Ax[j] into q.h)
    gemm_bt_split<<<dim3(BB * NN / 128, FOUT / 128, 1), 256, 0, stream>>>(
        hh, hl, aTh, aTl, qh, ql, a1, FOUT, FOUT);
    // attention: scores+P~ -> merge -> fused-rescale PV  (no fixup pass)
    pass_score<<<dim3(1024, 1, 1), 256, 0, stream>>>(
        qh, ql, hh, hl, adjm, Ay, mpm, mpl, P);
    ml_merge<<<(BB * NN) / 256, 256, 0, stream>>>(mpm, mpl, rs, fin);
    gemm_pv<<<dim3(512, 1, 1), 256, 0, stream>>>(
        P, featT, fagg, rs, fin);
    // h1 = feat @ W1 ; h2 = fagg @ W2
    gemm_bt<<<dim3(BB * NN / 128, FOUT / 128, 1), 256, 0, stream>>>(
        fh, W1T, h1, FOUT, FIN, 0, 0, 0);
    gemm_bt<<<dim3(BB * NN / 128, FOUT / 128, 1), 256, 0, stream>>>(
        fagg, W2T, h2, FOUT, FIN, 0, 0, 0);
    // e1 = feat @ Lw^T ; e2 = fagg @ Rw^T
    e_kernel<<<BB * NN / 4, 256, 0, stream>>>(fh, Lw, e1);
    e_kernel<<<BB * NN / 4, 256, 0, stream>>>(fagg, Rw, e2);
    // out = h1 + h2 + e1.Bw.e2
    final_kernel<<<BB * NN, FOUT, 0, stream>>>(out, h1, h2, e1, e2, Bw);
}

// Round 13
// 524.968 us; speedup vs baseline: 1.0073x; 1.0073x over previous
//
#include <hip/hip_runtime.h>
#include <hip/hip_bf16.h>

#define BB 8
#define NN 2048
#define FIN 512
#define FOUT 256
#define EE 5
#define ALPHA_ 0.2f
#define NEGV -9e15f
#define JW 512   // j-window per jz

typedef __hip_bfloat16 bf16;
typedef __bf16 bf16x8 __attribute__((ext_vector_type(8)));
typedef float f32x4 __attribute__((ext_vector_type(4)));
typedef unsigned long long u64;

__device__ __forceinline__ float bf2f(bf16 x) { return __bfloat162float(x); }
__device__ __forceinline__ bf16 f2bf(float x) { return __float2bfloat16(x); }

// async global->LDS, 16B per lane. LDS dest must be wave-uniform base + lane*16
// (true for all call sites: lds offset == idx*16B with idx = tid + i*256).
__device__ __forceinline__ void async16(const bf16* g, bf16* l) {
    __builtin_amdgcn_global_load_lds(
        (const __attribute__((address_space(1))) void*)g,
        (__attribute__((address_space(3))) void*)l, 16, 0, 0);
}

// LDS tile swizzle (both-sides transform, rule #21): tiles are [row][32] bf16 =
// row stride 64B; fragment reads at row*64 + quad*16 are an 8-way bank conflict.
// Permute the four 16B segments per row by seg ^= (row>>1)&3 on BOTH the global
// source (staging) and the LDS read offset. 8-way -> 2-way (free). Verified r3:
// SQ_LDS_BANK_CONFLICT = 0.
//
// Pipelined GEMM schedule (proven r0->r3/r8/r11): double-buffered LDS, prefetch
// before wait, counted s_waitcnt vmcnt(N) (never 0 mid-loop) + raw s_barrier,
// setprio(1) around MFMA. Buffer parity COMPILE-TIME (r5 lesson). Pipeline
// depth LOCKED at 1: r9's depth-3 halved occupancy and cost +59% (TLP-bound).
// pass_score XCD co-location REVERTED (r12: FETCH -42% but +1.2us -- kernel is
// latency-bound with TLP covering; traffic cuts don't move the critical path).

// ---------------- fused: split fp32->bf16 hi/lo (row-major) + bf16 transpose ----
// feat (67MB) read ONCE. r13 fix vs r12: float4 reads (16B/thread) + uint2
// hi/lo stores (8B) -- r12's scalar 2B stores ate the fusion's traffic win
// (Common-mistake #2). Transpose path = same 2B writes as baseline transpose.
__global__ void split_transpose(const float* __restrict__ in,
                                bf16* __restrict__ hi, bf16* __restrict__ lo,
                                bf16* __restrict__ outT) {
    __shared__ bf16 tile[32][33];
    long bi = (long)blockIdx.z * NN * FIN;   // feat / fh / fl base
    long bo = (long)blockIdx.z * FIN * NN;   // featT base
    int c0 = blockIdx.x * 32, r0 = blockIdx.y * 32;  // c = f, r = n
    int t = threadIdx.x;                  // 256 flat
    int xq = t & 7, yr = t >> 3;          // col-quad [0,8), row [0,32)
    {
        long idx = bi + (long)(r0 + yr) * FIN + c0 + xq * 4;
        float4 f = *(const float4*)(&in[idx]);
        float fv[4] = { f.x, f.y, f.z, f.w };
        alignas(8) bf16 h[4], l[4];
#pragma unroll
        for (int k = 0; k < 4; k++) {
            h[k] = f2bf(fv[k]);
            l[k] = f2bf(fv[k] - bf2f(h[k]));
            tile[yr][xq * 4 + k] = h[k];
        }
        *(uint2*)(&hi[idx]) = *(const uint2*)h;
        *(uint2*)(&lo[idx]) = *(const uint2*)l;
    }
    __syncthreads();
    int xo = t & 31, yo = t >> 5;         // n-idx [0,32), f-group [0,8)
#pragma unroll
    for (int k = 0; k < 4; k++) {
        int f = yo + k * 8;
        outT[bo + (long)(c0 + f) * NN + r0 + xo] = tile[xo][f];
    }
}

// ---------------- pack adj (int32 > 0) into 64-col bitmasks ----------------
__global__ void pack_adj(const int* __restrict__ adj, u64* __restrict__ adjm) {
    long wid = (((long)blockIdx.x * 256) + threadIdx.x) >> 6;
    int lane = threadIdx.x & 63;
    long base = wid * 256;
    for (int c = 0; c < 4; c++) {
        int a = adj[base + c * 64 + lane];
        u64 m = __ballot(a > 0);
        if (lane == 0) adjm[base / 64 + c] = m;
    }
}

// ---------------- transpose+split: fp32 [R,C] -> bf16 hi/lo [C,R] ----------------
__global__ void transpose_split(const float* __restrict__ in,
                                bf16* __restrict__ hi, bf16* __restrict__ lo,
                                int R, int C) {
    __shared__ bf16 th[32][33], tl[32][33];
    int c0 = blockIdx.x * 32, r0 = blockIdx.y * 32;
    int x = threadIdx.x, y = threadIdx.y;  // 32 x 8
    for (int k = 0; k < 4; k++) {
        int r = y + k * 8;
        float f = in[(long)(r0 + r) * C + c0 + x];
        bf16 h = f2bf(f);
        th[r][x] = h;
        tl[r][x] = f2bf(f - bf2f(h));
    }
    __syncthreads();
    for (int k = 0; k < 4; k++) {
        int r = y + k * 8;
        hi[(long)(c0 + r) * R + r0 + x] = th[x][r];
        lo[(long)(c0 + r) * R + r0 + x] = tl[x][r];
    }
}

// ---------------- transpose + convert: fp32 [R,C] -> bf16 [C,R] ----------------
__global__ void transpose_f32_bf16(const float* __restrict__ in, bf16* __restrict__ out,
                                   int R, int C, long sin_b, long sout_b) {
    __shared__ bf16 tile[32][33];
    long bi = (long)blockIdx.z * sin_b;
    long bo = (long)blockIdx.z * sout_b;
    int c0 = blockIdx.x * 32, r0 = blockIdx.y * 32;
    int x = threadIdx.x, y = threadIdx.y;
    for (int k = 0; k < 4; k++) {
        int r = y + k * 8;
        tile[r][x] = f2bf(in[bi + (long)(r0 + r) * C + c0 + x]);
    }
    __syncthreads();
    for (int k = 0; k < 4; k++) {
        int r = y + k * 8;
        out[bo + (long)(c0 + r) * R + r0 + x] = tile[x][r];
    }
}

// ---------------- split GEMM: C = (Ah+Al)[M,K] @ (Bh+Bl)[N,K]^T + bias ----------------
// Pipelined. 8 loads/step -> steady vmcnt(8), final vmcnt(0).
__global__ __launch_bounds__(256) void gemm_bt_split(
        const bf16* __restrict__ Ah, const bf16* __restrict__ Al,
        const bf16* __restrict__ Bh, const bf16* __restrict__ Bl,
        bf16* __restrict__ Chi, bf16* __restrict__ Clo,
        const float* __restrict__ bias, int Nn, int K) {
    __shared__ alignas(16) bf16 Ash[2][128 * 32], Asl[2][128 * 32];
    __shared__ alignas(16) bf16 Bsh[2][128 * 32], Bsl[2][128 * 32];
    int tid = threadIdx.x;
    int lane = tid & 63, ww = tid >> 6;
    int wm = ww >> 1, wn = ww & 1;
    int quad = lane >> 4, l16 = lane & 15;
    int qx = quad ^ ((l16 >> 1) & 3);            // swizzled read segment
    int sseg = (tid & 3) ^ ((tid >> 3) & 3);     // swizzled source segment (staging)
    int m0 = blockIdx.x * 128, n0 = blockIdx.y * 128;
    f32x4 acc[4][4] = {};
    auto STAGE = [&](int k0, int buf) {
#pragma unroll
        for (int i = 0; i < 2; i++) {
            int idx = tid + i * 256;
            int row = idx >> 2;
            long ao = (long)(m0 + row) * K + k0 + sseg * 8;
            long bo = (long)(n0 + row) * K + k0 + sseg * 8;
            async16(&Ah[ao], &Ash[buf][idx * 8]);
            async16(&Al[ao], &Asl[buf][idx * 8]);
            async16(&Bh[bo], &Bsh[buf][idx * 8]);
            async16(&Bl[bo], &Bsl[buf][idx * 8]);
        }
    };
    int nk = K / 32;   // even for all call sites (16 or 8)
    STAGE(0, 0);
    for (int s = 0; s < nk; s += 2) {
#pragma unroll
        for (int u = 0; u < 2; u++) {            // compile-time buffer parity
            int step = s + u;
            if (step + 1 < nk) STAGE((step + 1) * 32, u ^ 1);
            if (step + 1 < nk) asm volatile("s_waitcnt vmcnt(8)" ::: "memory");
            else               asm volatile("s_waitcnt vmcnt(0)" ::: "memory");
            __builtin_amdgcn_s_barrier();
            __builtin_amdgcn_sched_barrier(0);
            __builtin_amdgcn_s_setprio(1);
            bf16x8 afh[4], afl[4], bfh[4], bfl[4];
#pragma unroll
            for (int mi = 0; mi < 4; mi++) {
                int so = (wm * 64 + mi * 16 + l16) * 32 + qx * 8;
                afh[mi] = *(const bf16x8*)(&Ash[u][so]);
                afl[mi] = *(const bf16x8*)(&Asl[u][so]);
            }
#pragma unroll
            for (int ni = 0; ni < 4; ni++) {
                int so = (wn * 64 + ni * 16 + l16) * 32 + qx * 8;
                bfh[ni] = *(const bf16x8*)(&Bsh[u][so]);
                bfl[ni] = *(const bf16x8*)(&Bsl[u][so]);
            }
#pragma unroll
            for (int mi = 0; mi < 4; mi++)
#pragma unroll
                for (int ni = 0; ni < 4; ni++) {
                    acc[mi][ni] = __builtin_amdgcn_mfma_f32_16x16x32_bf16(afh[mi], bfh[ni], acc[mi][ni], 0, 0, 0);
                    acc[mi][ni] = __builtin_amdgcn_mfma_f32_16x16x32_bf16(afh[mi], bfl[ni], acc[mi][ni], 0, 0, 0);
                    acc[mi][ni] = __builtin_amdgcn_mfma_f32_16x16x32_bf16(afl[mi], bfh[ni], acc[mi][ni], 0, 0, 0);
                }
            __builtin_amdgcn_s_setprio(0);
            __builtin_amdgcn_sched_barrier(0);
            __builtin_amdgcn_s_barrier();        // readers done before buf[u] restaged
            __builtin_amdgcn_sched_barrier(0);
        }
    }
    for (int mi = 0; mi < 4; mi++)
        for (int ni = 0; ni < 4; ni++) {
            int col = n0 + wn * 64 + ni * 16 + l16;
            float bv = bias ? bias[col] : 0.f;
            for (int r = 0; r < 4; r++) {
                int row = m0 + wm * 64 + mi * 16 + quad * 4 + r;
                float v = acc[mi][ni][r] + bv;
                bf16 h = f2bf(v);
                Chi[(long)row * Nn + col] = h;
                Clo[(long)row * Nn + col] = f2bf(v - bf2f(h));
            }
        }
}

// ---------------- plain bf16 GEMM: C[M,N] = A[M,K] @ Bt[N,K]^T (pipelined) -----
__global__ __launch_bounds__(256) void gemm_bt(
        const bf16* __restrict__ A, const bf16* __restrict__ Bt,
        bf16* __restrict__ C, int Nn, int K, long sA, long sB, long sC) {
    __shared__ alignas(16) bf16 As[2][128 * 32];
    __shared__ alignas(16) bf16 Bs[2][128 * 32];
    const bf16* Ab = A + (long)blockIdx.z * sA;
    const bf16* Bb = Bt + (long)blockIdx.z * sB;
    bf16* Cb = C + (long)blockIdx.z * sC;
    int tid = threadIdx.x;
    int lane = tid & 63, ww = tid >> 6;
    int wm = ww >> 1, wn = ww & 1;
    int quad = lane >> 4, l16 = lane & 15;
    int qx = quad ^ ((l16 >> 1) & 3);
    int sseg = (tid & 3) ^ ((tid >> 3) & 3);
    int m0 = blockIdx.x * 128, n0 = blockIdx.y * 128;
    f32x4 acc[4][4] = {};
    auto STAGE = [&](int k0, int buf) {
#pragma unroll
        for (int i = 0; i < 2; i++) {
            int idx = tid + i * 256;
            int row = idx >> 2;
            async16(&Ab[(long)(m0 + row) * K + k0 + sseg * 8], &As[buf][idx * 8]);
            async16(&Bb[(long)(n0 + row) * K + k0 + sseg * 8], &Bs[buf][idx * 8]);
        }
    };
    int nk = K / 32;   // even for all call sites
    STAGE(0, 0);
    for (int s = 0; s < nk; s += 2) {
#pragma unroll
        for (int u = 0; u < 2; u++) {
            int step = s + u;
            if (step + 1 < nk) STAGE((step + 1) * 32, u ^ 1);
            if (step + 1 < nk) asm volatile("s_waitcnt vmcnt(4)" ::: "memory");
            else               asm volatile("s_waitcnt vmcnt(0)" ::: "memory");
            __builtin_amdgcn_s_barrier();
            __builtin_amdgcn_sched_barrier(0);
            __builtin_amdgcn_s_setprio(1);
            bf16x8 af[4], bfr[4];
#pragma unroll
            for (int mi = 0; mi < 4; mi++)
                af[mi] = *(const bf16x8*)(&As[u][(wm * 64 + mi * 16 + l16) * 32 + qx * 8]);
#pragma unroll
            for (int ni = 0; ni < 4; ni++)
                bfr[ni] = *(const bf16x8*)(&Bs[u][(wn * 64 + ni * 16 + l16) * 32 + qx * 8]);
#pragma unroll
            for (int mi = 0; mi < 4; mi++)
#pragma unroll
                for (int ni = 0; ni < 4; ni++)
                    acc[mi][ni] = __builtin_amdgcn_mfma_f32_16x16x32_bf16(
                        af[mi], bfr[ni], acc[mi][ni], 0, 0, 0);
            __builtin_amdgcn_s_setprio(0);
            __builtin_amdgcn_sched_barrier(0);
            __builtin_amdgcn_s_barrier();
            __builtin_amdgcn_sched_barrier(0);
        }
    }
    for (int mi = 0; mi < 4; mi++)
        for (int ni = 0; ni < 4; ni++) {
            int col = n0 + wn * 64 + ni * 16 + l16;
            for (int r = 0; r < 4; r++) {
                int row = m0 + wm * 64 + mi * 16 + quad * 4 + r;
                Cb[(long)row * Nn + col] = f2bf(acc[mi][ni][r]);
            }
        }
}

// ---------------- PV GEMM with fused per-chunk softmax rescale (FA-style) -----
// Pipelined like gemm_bt. XCD-aware block swizzle (T1): 1-D grid of 512; the 4
// n-blocks sharing one P m-panel map to consecutive slots on the SAME XCD.
__global__ __launch_bounds__(256) void gemm_pv(
        const bf16* __restrict__ A, const bf16* __restrict__ Bt,
        bf16* __restrict__ C, const float* __restrict__ rs,
        const float* __restrict__ fin) {
    __shared__ alignas(16) bf16 As[2][128 * 32];
    __shared__ alignas(16) bf16 Bs[2][128 * 32];
    int flat = blockIdx.x;                 // [0,512)
    int xcd = flat & 7, j = flat >> 3;     // round-robin XCD assumption
    int panel = xcd * 16 + (j >> 2);       // [0,128) = (b,m) panel
    int b = panel >> 4;
    int m0 = (panel & 15) * 128;
    int n0 = (j & 3) * 128;
    const bf16* Ab = A + (long)b * NN * NN;
    const bf16* Bb = Bt + (long)b * FIN * NN;
    bf16* Cb = C + (long)b * NN * FIN;
    int tid = threadIdx.x;
    int lane = tid & 63, ww = tid >> 6;
    int wm = ww >> 1, wn = ww & 1;
    int quad = lane >> 4, l16 = lane & 15;
    int qx = quad ^ ((l16 >> 1) & 3);
    int sseg = (tid & 3) ^ ((tid >> 3) & 3);
    f32x4 acc[4][4] = {};
    auto STAGE = [&](int k0, int buf) {
#pragma unroll
        for (int i = 0; i < 2; i++) {
            int idx = tid + i * 256;
            int row = idx >> 2;
            async16(&Ab[(long)(m0 + row) * NN + k0 + sseg * 8], &As[buf][idx * 8]);
            async16(&Bb[(long)(n0 + row) * NN + k0 + sseg * 8], &Bs[buf][idx * 8]);
        }
    };
    const int nk = NN / 32;  // 64
    STAGE(0, 0);
    for (int s = 0; s < nk; s += 2) {
#pragma unroll
        for (int u = 0; u < 2; u++) {
            int step = s + u;
            int k0 = step * 32;
            if (k0 && !(k0 & 127)) {          // entering chunk c: rescale acc
                int c = k0 >> 7;
#pragma unroll
                for (int mi = 0; mi < 4; mi++) {
                    float4 rv = *(const float4*)(&rs[((long)b * 16 + c) * NN
                                                     + m0 + wm * 64 + mi * 16 + quad * 4]);
#pragma unroll
                    for (int ni = 0; ni < 4; ni++) {
                        acc[mi][ni][0] *= rv.x;
                        acc[mi][ni][1] *= rv.y;
                        acc[mi][ni][2] *= rv.z;
                        acc[mi][ni][3] *= rv.w;
                    }
                }
            }
            if (step + 1 < nk) STAGE((step + 1) * 32, u ^ 1);
            if (step + 1 < nk) asm volatile("s_waitcnt vmcnt(4)" ::: "memory");
            else               asm volatile("s_waitcnt vmcnt(0)" ::: "memory");
            __builtin_amdgcn_s_barrier();
            __builtin_amdgcn_sched_barrier(0);
            __builtin_amdgcn_s_setprio(1);
            bf16x8 af[4], bfr[4];
#pragma unroll
            for (int mi = 0; mi < 4; mi++)
                af[mi] = *(const bf16x8*)(&As[u][(wm * 64 + mi * 16 + l16) * 32 + qx * 8]);
#pragma unroll
            for (int ni = 0; ni < 4; ni++)
                bfr[ni] = *(const bf16x8*)(&Bs[u][(wn * 64 + ni * 16 + l16) * 32 + qx * 8]);
#pragma unroll
            for (int mi = 0; mi < 4; mi++)
#pragma unroll
                for (int ni = 0; ni < 4; ni++)
                    acc[mi][ni] = __builtin_amdgcn_mfma_f32_16x16x32_bf16(
                        af[mi], bfr[ni], acc[mi][ni], 0, 0, 0);
            __builtin_amdgcn_s_setprio(0);
            __builtin_amdgcn_sched_barrier(0);
            __builtin_amdgcn_s_barrier();
            __builtin_amdgcn_sched_barrier(0);
        }
    }
    for (int mi = 0; mi < 4; mi++) {
        float4 fv = *(const float4*)(&fin[(long)b * NN + m0 + wm * 64 + mi * 16 + quad * 4]);
        for (int ni = 0; ni < 4; ni++) {
            int col = n0 + wn * 64 + ni * 16 + l16;
            float fvr[4] = { fv.x, fv.y, fv.z, fv.w };
            for (int r = 0; r < 4; r++) {
                int row = m0 + wm * 64 + mi * 16 + quad * 4 + r;
                Cb[(long)row * FIN + col] = f2bf(acc[mi][ni][r] * fvr[r]);
            }
        }
    }
}

// ---------------- Ay[b,n] = (hh+hl)[b,n,:] . a2 ----------------
__global__ void ay_kernel(const bf16* __restrict__ hh, const bf16* __restrict__ hl,
                          const float* __restrict__ a2, float* __restrict__ Ay) {
    int lane = threadIdx.x & 63, w = threadIdx.x >> 6;
    long row = (long)blockIdx.x * 4 + w;
    float p = 0.f;
    for (int i = 0; i < 4; i++) {
        int d = i * 64 + lane;
        p += (bf2f(hh[row * FOUT + d]) + bf2f(hl[row * FOUT + d])) * a2[d];
    }
    for (int off = 32; off; off >>= 1) p += __shfl_xor(p, off);
    if (lane == 0) Ay[row] = p;
}

// ---------------- single score pass: stats + unnormalized P~ (all 8 batches) ----------------
// r8/r11-verbatim (proven best: 92.7-93.6us, VGPR 120, FETCH 78MB, conflicts 0).
// Schedule arc CLOSED: depth-1/2-buffer optimal (M_rep=2 r4/r7, 1-barrier r5,
// depth-3 r9 refuted). r12's XCD co-location REVERTED: FETCH -42% but +1.2us
// (latency-bound, TLP covers -- traffic cuts don't move the critical path).
__global__ __launch_bounds__(256) void pass_score(
        const bf16* __restrict__ qh_, const bf16* __restrict__ ql_,
        const bf16* __restrict__ hh_, const bf16* __restrict__ hl_,
        const u64* __restrict__ adjm, const float* __restrict__ Ay,
        float* __restrict__ mpm, float* __restrict__ mpl,
        bf16* __restrict__ P) {
    __shared__ alignas(16) bf16 Hsh[2][128 * 32], Hsl[2][128 * 32];
    __shared__ alignas(16) bf16 pst[4][16 * 64];   // per-wave 16x64 half-tile, swizzled
    int tid = threadIdx.x;
    int lane = tid & 63, w = tid >> 6;
    int quad = lane >> 4, l16 = lane & 15;
    int qx = quad ^ ((l16 >> 1) & 3);            // swizzled read segment
    int sseg = (tid & 3) ^ ((tid >> 3) & 3);     // swizzled source segment (staging)
    int b = blockIdx.z, jz = blockIdx.y;
    int i0 = blockIdx.x * 64 + w * 16;
    long qoff = ((long)b * NN + i0) * FOUT;
    const bf16* hbh = hh_ + ((long)b * NN + (long)jz * JW) * FOUT;
    const bf16* hbl = hl_ + ((long)b * NN + (long)jz * JW) * FOUT;
    const u64* amb = adjm + ((long)b * NN + i0) * (NN / 64) + jz * (JW / 64);
    bf16* pw = pst[w];

    bf16x8 qfh[8], qfl[8];
#pragma unroll
    for (int kk = 0; kk < 8; kk++) {
        qfh[kk] = *(const bf16x8*)(&qh_[qoff + (long)l16 * FOUT + kk * 32 + quad * 8]);
        qfl[kk] = *(const bf16x8*)(&ql_[qoff + (long)l16 * FOUT + kk * 32 + quad * 8]);
    }
    float ay_[4];
#pragma unroll
    for (int r = 0; r < 4; r++) ay_[r] = Ay[(long)b * NN + i0 + quad * 4 + r];

    float m_[4], l_[4];
#pragma unroll
    for (int r = 0; r < 4; r++) { m_[r] = -3.0e38f; l_[r] = 0.f; }

    // stage (jc,kk) into buffer `buf`: 4 global_load_lds/thread (source-swizzled)
    auto STAGE = [&](int jc, int kk, int buf) {
#pragma unroll
        for (int i = 0; i < 2; i++) {
            int idx = tid + i * 256;
            int row = idx >> 2;
            long go = (long)(jc * 128 + row) * FOUT + kk * 32 + sseg * 8;
            async16(&hbh[go], &Hsh[buf][idx * 8]);
            async16(&hbl[go], &Hsl[buf][idx * 8]);
        }
    };

    f32x4 sacc[8];
#pragma unroll
    for (int ni = 0; ni < 8; ni++) sacc[ni] = (f32x4){0.f, 0.f, 0.f, 0.f};

    STAGE(0, 0, 0);
    for (int jc = 0; jc < 4; jc++) {          // runtime loop (uniform)
#pragma unroll
        for (int kk = 0; kk < 8; kk++) {      // compile-time: qfh[kk] stays in VGPRs
            const int cur = kk & 1;           // jc*8 is even -> buf parity = kk&1
            // prefetch next step into the other buffer
            if (kk < 7)           STAGE(jc, kk + 1, cur ^ 1);
            else if (jc < 3)      STAGE(jc + 1, 0, cur ^ 1);
            // wait until STAGE(jc,kk) landed; keep newest prefetch in flight
            if (kk == 0) {
                if (jc == 0) asm volatile("s_waitcnt vmcnt(4)" ::: "memory");
                else         asm volatile("s_waitcnt vmcnt(8)" ::: "memory");
            } else if (kk == 7 && jc == 3) {
                asm volatile("s_waitcnt vmcnt(0)" ::: "memory");
            } else {
                asm volatile("s_waitcnt vmcnt(4)" ::: "memory");
            }
            __builtin_amdgcn_s_barrier();     // buf[cur] staged for all waves
            __builtin_amdgcn_sched_barrier(0);

            __builtin_amdgcn_s_setprio(1);
#pragma unroll
            for (int ni = 0; ni < 8; ni++) {
                int so = (ni * 16 + l16) * 32 + qx * 8;
                bf16x8 hfh = *(const bf16x8*)(&Hsh[cur][so]);
                bf16x8 hfl = *(const bf16x8*)(&Hsl[cur][so]);
                sacc[ni] = __builtin_amdgcn_mfma_f32_16x16x32_bf16(qfh[kk], hfh, sacc[ni], 0, 0, 0);
                sacc[ni] = __builtin_amdgcn_mfma_f32_16x16x32_bf16(qfh[kk], hfl, sacc[ni], 0, 0, 0);
                sacc[ni] = __builtin_amdgcn_mfma_f32_16x16x32_bf16(qfl[kk], hfh, sacc[ni], 0, 0, 0);
            }
            __builtin_amdgcn_s_setprio(0);

            if (kk == 7) {
                // ---- epilogue for this jc: mask + leaky relu + online softmax ----
                u64 am[4][2];
#pragma unroll
                for (int r = 0; r < 4; r++) {
                    am[r][0] = amb[(long)(quad * 4 + r) * (NN / 64) + jc * 2 + 0];
                    am[r][1] = amb[(long)(quad * 4 + r) * (NN / 64) + jc * 2 + 1];
                }
#pragma unroll
                for (int ni = 0; ni < 8; ni++)
#pragma unroll
                    for (int r = 0; r < 4; r++) {
                        float v = sacc[ni][r] + ay_[r];
                        v = v > 0.f ? v : ALPHA_ * v;
                        int bit = (int)((am[r][ni >> 2] >> ((ni * 16 + l16) & 63)) & 1);
                        sacc[ni][r] = bit ? v : NEGV;
                    }
#pragma unroll
                for (int r = 0; r < 4; r++) {
                    float mc = -3.0e38f;
#pragma unroll
                    for (int ni = 0; ni < 8; ni++) mc = fmaxf(mc, sacc[ni][r]);
                    for (int off = 8; off; off >>= 1) mc = fmaxf(mc, __shfl_xor(mc, off));
                    float mnew = fmaxf(m_[r], mc);
                    float scale = __expf(m_[r] - mnew);
                    float ps = 0.f;
#pragma unroll
                    for (int ni = 0; ni < 8; ni++) {
                        float p = __expf(sacc[ni][r] - mnew);
                        sacc[ni][r] = p;
                        ps += p;
                    }
                    for (int off = 8; off; off >>= 1) ps += __shfl_xor(ps, off);
                    l_[r] = l_[r] * scale + ps;
                    m_[r] = mnew;
                    if (l16 == 0)
                        mpm[(((long)b * 4 + jz) * 4 + jc) * NN + i0 + quad * 4 + r] = mnew;
                }
                // ---- P~ store via swizzled per-wave LDS half-tiles (2 rounds) ----
#pragma unroll
                for (int h = 0; h < 2; h++) {
#pragma unroll
                    for (int ni = 0; ni < 4; ni++)
#pragma unroll
                        for (int r = 0; r < 4; r++) {
                            int row = quad * 4 + r;
                            int byt = (row * 128 + (ni * 16 + l16) * 2) ^ ((row & 7) << 4);
                            *(bf16*)((char*)pw + byt) = f2bf(sacc[h * 4 + ni][r]);
                        }
#pragma unroll
                    for (int s2 = 0; s2 < 2; s2++) {
                        int cq = quad + s2 * 4;
                        int byt = (l16 * 128 + cq * 16) ^ ((l16 & 7) << 4);
                        uint4 v = *(const uint4*)((const char*)pw + byt);
                        *(uint4*)(&P[((long)b * NN + i0 + l16) * NN + (long)jz * JW
                                     + jc * 128 + h * 64 + cq * 8]) = v;
                    }
                }
#pragma unroll
                for (int ni = 0; ni < 8; ni++) sacc[ni] = (f32x4){0.f, 0.f, 0.f, 0.f};
            }
            __builtin_amdgcn_sched_barrier(0);
            __builtin_amdgcn_s_barrier();   // all waves done reading buf[cur] before restage
            __builtin_amdgcn_sched_barrier(0);
        }
    }
    if (l16 == 0)
#pragma unroll
        for (int r = 0; r < 4; r++)
            mpl[((long)b * 4 + jz) * NN + i0 + quad * 4 + r] = l_[r];
}

// ---------------- merge window stats -> chunk ratios rs + final scale fin ----------------
// rs[b,c,n] = exp(m_{c-1} - m_c)  (c=1..15; c=0 unused)
// fin[b,n]  = exp(m_15 - m_glob) / l_glob
__global__ void ml_merge(const float* __restrict__ mpm, const float* __restrict__ mpl,
                         float* __restrict__ rs, float* __restrict__ fin) {
    long row = (long)blockIdx.x * blockDim.x + threadIdx.x;  // [0, BB*NN)
    long b = row / NN, n = row % NN;
    float mc[16];
#pragma unroll
    for (int c = 0; c < 16; c++) mc[c] = mpm[(b * 16 + c) * NN + n];
    float m = fmaxf(fmaxf(mc[3], mc[7]), fmaxf(mc[11], mc[15]));
    float l = 0.f;
#pragma unroll
    for (int jz = 0; jz < 4; jz++)
        l += mpl[(b * 4 + jz) * NN + n] * __expf(mc[jz * 4 + 3] - m);
    fin[row] = __expf(mc[15] - m) / l;
#pragma unroll
    for (int c = 1; c < 16; c++)
        rs[(b * 16 + c) * NN + n] = __expf(mc[c - 1] - mc[c]);
}

// ---------------- e = X_bf16[*,512] @ W_f32[5,512]^T (fp32 out) ----------------
__global__ void e_kernel(const bf16* __restrict__ X, const float* __restrict__ Wt,
                         float* __restrict__ out) {
    int lane = threadIdx.x & 63, w = threadIdx.x >> 6;
    long row = (long)blockIdx.x * 4 + w;
    uint4 raw = *(const uint4*)(&X[row * FIN + lane * 8]);
    const bf16* xp = (const bf16*)&raw;
    float xv[8];
    for (int i = 0; i < 8; i++) xv[i] = bf2f(xp[i]);
    for (int e = 0; e < EE; e++) {
        float4 w0 = *(const float4*)(&Wt[e * FIN + lane * 8]);
        float4 w1 = *(const float4*)(&Wt[e * FIN + lane * 8 + 4]);
        float p = xv[0] * w0.x + xv[1] * w0.y + xv[2] * w0.z + xv[3] * w0.w
                + xv[4] * w1.x + xv[5] * w1.y + xv[6] * w1.z + xv[7] * w1.w;
        for (int off = 32; off; off >>= 1) p += __shfl_xor(p, off);
        if (lane == 0) out[row * EE + e] = p;
    }
}

// ---------------- out(fp32) = h1 + h2 + e1.Bw.e2 ----------------
__global__ void final_kernel(float* __restrict__ out,
                             const bf16* __restrict__ h1, const bf16* __restrict__ h2,
                             const float* __restrict__ e1, const float* __restrict__ e2,
                             const float* __restrict__ Bw) {
    long row = blockIdx.x;
    int o = threadIdx.x;
    float a[EE], c[EE];
    for (int i = 0; i < EE; i++) { a[i] = e1[row * EE + i]; c[i] = e2[row * EE + i]; }
    const float* bw = Bw + (long)o * EE * EE;
    float acc = 0.f;
    for (int i = 0; i < EE; i++)
        for (int j = 0; j < EE; j++)
            acc += bw[i * EE + j] * a[i] * c[j];
    long idx = row * FOUT + o;
    out[idx] = acc + bf2f(h1[idx]) + bf2f(h2[idx]);
}

extern "C" void kernel_launch(void* const* d_in, const int* in_sizes, int n_in,
                              void* d_out, int out_size, void* d_ws, size_t ws_size,
                              hipStream_t stream) {
    const float* feat = (const float*)d_in[0];
    const int*   adj  = (const int*)d_in[1];
    const float* W    = (const float*)d_in[2];
    const float* W1   = (const float*)d_in[3];
    const float* W2   = (const float*)d_in[4];
    const float* a1   = (const float*)d_in[5];
    const float* a2   = (const float*)d_in[6];
    const float* a12  = (const float*)d_in[7];
    const float* Lw   = (const float*)d_in[8];
    const float* Rw   = (const float*)d_in[9];
    const float* Bw   = (const float*)d_in[10];
    float* out = (float*)d_out;

    char* ws = (char*)d_ws;
    size_t off = 0;
    auto alloc = [&](size_t bytes) {
        char* p = ws + off;
        off += (bytes + 255) & ~(size_t)255;
        return p;
    };
    bf16* WTh  = (bf16*)alloc((size_t)FOUT * FIN * 2);
    bf16* WTl  = (bf16*)alloc((size_t)FOUT * FIN * 2);
    bf16* W1T  = (bf16*)alloc((size_t)FOUT * FIN * 2);
    bf16* W2T  = (bf16*)alloc((size_t)FOUT * FIN * 2);
    bf16* aTh  = (bf16*)alloc((size_t)FOUT * FOUT * 2);
    bf16* aTl  = (bf16*)alloc((size_t)FOUT * FOUT * 2);
    bf16* fh   = (bf16*)alloc((size_t)BB * NN * FIN * 2);     // 16.8 MB
    bf16* fl   = (bf16*)alloc((size_t)BB * NN * FIN * 2);     // 16.8 MB (fagg later)
    bf16* hh   = (bf16*)alloc((size_t)BB * NN * FOUT * 2);    // 8.4 MB (h1 later)
    bf16* hl   = (bf16*)alloc((size_t)BB * NN * FOUT * 2);    // 8.4 MB (h2 later)
    bf16* featT= (bf16*)alloc((size_t)BB * NN * FIN * 2);     // 16.8 MB
    float* Ay  = (float*)alloc((size_t)BB * NN * 4);
    float* mpm = (float*)alloc((size_t)BB * 4 * 4 * NN * 4);  // 1 MB
    float* mpl = (float*)alloc((size_t)BB * 4 * NN * 4);      // 256 KB
    float* rs  = (float*)alloc((size_t)BB * 16 * NN * 4);     // 2 MB chunk ratios
    float* fin = (float*)alloc((size_t)BB * NN * 4);          // 64 KB final scales
    float* e1  = (float*)alloc((size_t)BB * NN * EE * 4);
    float* e2  = (float*)alloc((size_t)BB * NN * EE * 4);
    u64* adjm  = (u64*)alloc((size_t)BB * NN * (NN / 64) * 8);// 4.2 MB
    bf16* P    = (bf16*)alloc((size_t)BB * NN * NN * 2);      // 67.1 MB (all batches)
    // aliases (lifetimes disjoint):  peak ws ~140 MB (ws is ~512 MB)
    bf16* qh   = (bf16*)d_out;                          // q pair in out (16.8 MB)
    bf16* ql   = qh + (size_t)BB * NN * FOUT;
    bf16* fagg = fl;                                    // fl dead after h-GEMM
    bf16* h1   = hh;                                    // h pair dead after scores
    bf16* h2   = hl;

    dim3 tb(32, 8, 1);
    // input conversions (feat read ONCE: split + featT transpose fused, vectorized)
    split_transpose<<<dim3(FIN / 32, NN / 32, BB), 256, 0, stream>>>(feat, fh, fl, featT);
    pack_adj<<<(BB * NN * NN) / (256 * 4), 256, 0, stream>>>(adj, adjm);
    transpose_split<<<dim3(FOUT / 32, FIN / 32, 1), tb, 0, stream>>>(W, WTh, WTl, FIN, FOUT);
    transpose_split<<<dim3(FOUT / 32, FOUT / 32, 1), tb, 0, stream>>>(a12, aTh, aTl, FOUT, FOUT);
    transpose_f32_bf16<<<dim3(FOUT / 32, FIN / 32, 1), tb, 0, stream>>>(W1, W1T, FIN, FOUT, 0, 0);
    transpose_f32_bf16<<<dim3(FOUT / 32, FIN / 32, 1), tb, 0, stream>>>(W2, W2T, FIN, FOUT, 0, 0);
    // h = feat @ W   (split precision)
    gemm_bt_split<<<dim3(BB * NN / 128, FOUT / 128, 1), 256, 0, stream>>>(
        fh, fl, WTh, WTl, hh, hl, nullptr, FOUT, FIN);
    // Ay = h @ a2
    ay_kernel<<<BB * NN / 4, 256, 0, stream>>>(hh, hl, a2, Ay);
    // q = h @ a12 + a1   (folds Ax[j] into q.h)
    gemm_bt_split<<<dim3(BB * NN / 128, FOUT / 128, 1), 256, 0, stream>>>(
        hh, hl, aTh, aTl, qh, ql, a1, FOUT, FOUT);
    // attention: scores+P~ -> merge -> fused-rescale PV  (no fixup pass)
    pass_score<<<dim3(NN / 64, 4, BB), 256, 0, stream>>>(
        qh, ql, hh, hl, adjm, Ay, mpm, mpl, P);
    ml_merge<<<(BB * NN) / 256, 256, 0, stream>>>(mpm, mpl, rs, fin);
    gemm_pv<<<dim3(512, 1, 1), 256, 0, stream>>>(
        P, featT, fagg, rs, fin);
    // h1 = feat @ W1 ; h2 = fagg @ W2
    gemm_bt<<<dim3(BB * NN / 128, FOUT / 128, 1), 256, 0, stream>>>(
        fh, W1T, h1, FOUT, FIN, 0, 0, 0);
    gemm_bt<<<dim3(BB * NN / 128, FOUT / 128, 1), 256, 0, stream>>>(
        fagg, W2T, h2, FOUT, FIN, 0, 0, 0);
    // e1 = feat @ Lw^T ; e2 = fagg @ Rw^T
    e_kernel<<<BB * NN / 4, 256, 0, stream>>>(fh, Lw, e1);
    e_kernel<<<BB * NN / 4, 256, 0, stream>>>(fagg, Rw, e2);
    // out = h1 + h2 + e1.Bw.e2
    final_kernel<<<BB * NN, FOUT, 0, stream>>>(out, h1, h2, e1, e2, Bw);
}

// Round 14
// 519.408 us; speedup vs baseline: 1.0180x; 1.0107x over previous
//
#include <hip/hip_runtime.h>
#include <hip/hip_bf16.h>

#define BB 8
#define NN 2048
#define FIN 512
#define FOUT 256
#define EE 5
#define ALPHA_ 0.2f
#define NEGV -9e15f
#define JW 512   // j-window per jz

typedef __hip_bfloat16 bf16;
typedef __bf16 bf16x8 __attribute__((ext_vector_type(8)));
typedef float f32x4 __attribute__((ext_vector_type(4)));
typedef unsigned long long u64;

__device__ __forceinline__ float bf2f(bf16 x) { return __bfloat162float(x); }
__device__ __forceinline__ bf16 f2bf(float x) { return __float2bfloat16(x); }

// async global->LDS, 16B per lane. LDS dest must be wave-uniform base + lane*16
// (true for all call sites: lds offset == idx*16B with idx = tid + i*256).
__device__ __forceinline__ void async16(const bf16* g, bf16* l) {
    __builtin_amdgcn_global_load_lds(
        (const __attribute__((address_space(1))) void*)g,
        (__attribute__((address_space(3))) void*)l, 16, 0, 0);
}

// LDS tile swizzle (both-sides transform, rule #21): tiles are [row][32] bf16 =
// row stride 64B; fragment reads at row*64 + quad*16 are an 8-way bank conflict.
// Permute the four 16B segments per row by seg ^= (row>>1)&3 on BOTH the global
// source (staging) and the LDS read offset. 8-way -> 2-way (free). Verified r3:
// SQ_LDS_BANK_CONFLICT = 0.
//
// Pipelined GEMM schedule (proven r0->r3/r8/r11): double-buffered LDS, prefetch
// before wait, counted s_waitcnt vmcnt(N) (never 0 mid-loop) + raw s_barrier,
// setprio(1) around MFMA. Buffer parity COMPILE-TIME (r5 lesson). Pipeline
// depth LOCKED at 1: r9's depth-3 halved occupancy, +59% (TLP-bound).
// REFUTED and reverted: pass_score XCD co-location (r12: FETCH -42% but +1.2us,
// latency-bound with TLP covering); feat split+transpose fusion (r12/r13: -6 to
// -8us both scalar and vectorized -- the saved 67MB re-read was L3-absorbed).
// This file = r11 configuration verbatim (best measured: 519.7us).

// ---------------- split fp32 -> bf16 (hi, lo), flat, 8/thread ----------------
__global__ void split_f32_bf16(const float* __restrict__ in,
                               bf16* __restrict__ hi, bf16* __restrict__ lo) {
    long i = ((long)blockIdx.x * blockDim.x + threadIdx.x) * 8;
    float4 a = *(const float4*)(&in[i]);
    float4 b = *(const float4*)(&in[i + 4]);
    float x[8] = { a.x, a.y, a.z, a.w, b.x, b.y, b.z, b.w };
    bf16 th[8], tl[8];
    for (int k = 0; k < 8; k++) {
        th[k] = f2bf(x[k]);
        tl[k] = f2bf(x[k] - bf2f(th[k]));
    }
    *(uint4*)(&hi[i]) = *(const uint4*)th;
    *(uint4*)(&lo[i]) = *(const uint4*)tl;
}

// ---------------- pack adj (int32 > 0) into 64-col bitmasks ----------------
__global__ void pack_adj(const int* __restrict__ adj, u64* __restrict__ adjm) {
    long wid = (((long)blockIdx.x * 256) + threadIdx.x) >> 6;
    int lane = threadIdx.x & 63;
    long base = wid * 256;
    for (int c = 0; c < 4; c++) {
        int a = adj[base + c * 64 + lane];
        u64 m = __ballot(a > 0);
        if (lane == 0) adjm[base / 64 + c] = m;
    }
}

// ---------------- transpose+split: fp32 [R,C] -> bf16 hi/lo [C,R] ----------------
__global__ void transpose_split(const float* __restrict__ in,
                                bf16* __restrict__ hi, bf16* __restrict__ lo,
                                int R, int C) {
    __shared__ bf16 th[32][33], tl[32][33];
    int c0 = blockIdx.x * 32, r0 = blockIdx.y * 32;
    int x = threadIdx.x, y = threadIdx.y;  // 32 x 8
    for (int k = 0; k < 4; k++) {
        int r = y + k * 8;
        float f = in[(long)(r0 + r) * C + c0 + x];
        bf16 h = f2bf(f);
        th[r][x] = h;
        tl[r][x] = f2bf(f - bf2f(h));
    }
    __syncthreads();
    for (int k = 0; k < 4; k++) {
        int r = y + k * 8;
        hi[(long)(c0 + r) * R + r0 + x] = th[x][r];
        lo[(long)(c0 + r) * R + r0 + x] = tl[x][r];
    }
}

// ---------------- transpose + convert: fp32 [R,C] -> bf16 [C,R] ----------------
__global__ void transpose_f32_bf16(const float* __restrict__ in, bf16* __restrict__ out,
                                   int R, int C, long sin_b, long sout_b) {
    __shared__ bf16 tile[32][33];
    long bi = (long)blockIdx.z * sin_b;
    long bo = (long)blockIdx.z * sout_b;
    int c0 = blockIdx.x * 32, r0 = blockIdx.y * 32;
    int x = threadIdx.x, y = threadIdx.y;
    for (int k = 0; k < 4; k++) {
        int r = y + k * 8;
        tile[r][x] = f2bf(in[bi + (long)(r0 + r) * C + c0 + x]);
    }
    __syncthreads();
    for (int k = 0; k < 4; k++) {
        int r = y + k * 8;
        out[bo + (long)(c0 + r) * R + r0 + x] = tile[x][r];
    }
}

// ---------------- split GEMM: C = (Ah+Al)[M,K] @ (Bh+Bl)[N,K]^T + bias ----------------
// Pipelined. 8 loads/step -> steady vmcnt(8), final vmcnt(0).
__global__ __launch_bounds__(256) void gemm_bt_split(
        const bf16* __restrict__ Ah, const bf16* __restrict__ Al,
        const bf16* __restrict__ Bh, const bf16* __restrict__ Bl,
        bf16* __restrict__ Chi, bf16* __restrict__ Clo,
        const float* __restrict__ bias, int Nn, int K) {
    __shared__ alignas(16) bf16 Ash[2][128 * 32], Asl[2][128 * 32];
    __shared__ alignas(16) bf16 Bsh[2][128 * 32], Bsl[2][128 * 32];
    int tid = threadIdx.x;
    int lane = tid & 63, ww = tid >> 6;
    int wm = ww >> 1, wn = ww & 1;
    int quad = lane >> 4, l16 = lane & 15;
    int qx = quad ^ ((l16 >> 1) & 3);            // swizzled read segment
    int sseg = (tid & 3) ^ ((tid >> 3) & 3);     // swizzled source segment (staging)
    int m0 = blockIdx.x * 128, n0 = blockIdx.y * 128;
    f32x4 acc[4][4] = {};
    auto STAGE = [&](int k0, int buf) {
#pragma unroll
        for (int i = 0; i < 2; i++) {
            int idx = tid + i * 256;
            int row = idx >> 2;
            long ao = (long)(m0 + row) * K + k0 + sseg * 8;
            long bo = (long)(n0 + row) * K + k0 + sseg * 8;
            async16(&Ah[ao], &Ash[buf][idx * 8]);
            async16(&Al[ao], &Asl[buf][idx * 8]);
            async16(&Bh[bo], &Bsh[buf][idx * 8]);
            async16(&Bl[bo], &Bsl[buf][idx * 8]);
        }
    };
    int nk = K / 32;   // even for all call sites (16 or 8)
    STAGE(0, 0);
    for (int s = 0; s < nk; s += 2) {
#pragma unroll
        for (int u = 0; u < 2; u++) {            // compile-time buffer parity
            int step = s + u;
            if (step + 1 < nk) STAGE((step + 1) * 32, u ^ 1);
            if (step + 1 < nk) asm volatile("s_waitcnt vmcnt(8)" ::: "memory");
            else               asm volatile("s_waitcnt vmcnt(0)" ::: "memory");
            __builtin_amdgcn_s_barrier();
            __builtin_amdgcn_sched_barrier(0);
            __builtin_amdgcn_s_setprio(1);
            bf16x8 afh[4], afl[4], bfh[4], bfl[4];
#pragma unroll
            for (int mi = 0; mi < 4; mi++) {
                int so = (wm * 64 + mi * 16 + l16) * 32 + qx * 8;
                afh[mi] = *(const bf16x8*)(&Ash[u][so]);
                afl[mi] = *(const bf16x8*)(&Asl[u][so]);
            }
#pragma unroll
            for (int ni = 0; ni < 4; ni++) {
                int so = (wn * 64 + ni * 16 + l16) * 32 + qx * 8;
                bfh[ni] = *(const bf16x8*)(&Bsh[u][so]);
                bfl[ni] = *(const bf16x8*)(&Bsl[u][so]);
            }
#pragma unroll
            for (int mi = 0; mi < 4; mi++)
#pragma unroll
                for (int ni = 0; ni < 4; ni++) {
                    acc[mi][ni] = __builtin_amdgcn_mfma_f32_16x16x32_bf16(afh[mi], bfh[ni], acc[mi][ni], 0, 0, 0);
                    acc[mi][ni] = __builtin_amdgcn_mfma_f32_16x16x32_bf16(afh[mi], bfl[ni], acc[mi][ni], 0, 0, 0);
                    acc[mi][ni] = __builtin_amdgcn_mfma_f32_16x16x32_bf16(afl[mi], bfh[ni], acc[mi][ni], 0, 0, 0);
                }
            __builtin_amdgcn_s_setprio(0);
            __builtin_amdgcn_sched_barrier(0);
            __builtin_amdgcn_s_barrier();        // readers done before buf[u] restaged
            __builtin_amdgcn_sched_barrier(0);
        }
    }
    for (int mi = 0; mi < 4; mi++)
        for (int ni = 0; ni < 4; ni++) {
            int col = n0 + wn * 64 + ni * 16 + l16;
            float bv = bias ? bias[col] : 0.f;
            for (int r = 0; r < 4; r++) {
                int row = m0 + wm * 64 + mi * 16 + quad * 4 + r;
                float v = acc[mi][ni][r] + bv;
                bf16 h = f2bf(v);
                Chi[(long)row * Nn + col] = h;
                Clo[(long)row * Nn + col] = f2bf(v - bf2f(h));
            }
        }
}

// ---------------- plain bf16 GEMM: C[M,N] = A[M,K] @ Bt[N,K]^T (pipelined) -----
__global__ __launch_bounds__(256) void gemm_bt(
        const bf16* __restrict__ A, const bf16* __restrict__ Bt,
        bf16* __restrict__ C, int Nn, int K, long sA, long sB, long sC) {
    __shared__ alignas(16) bf16 As[2][128 * 32];
    __shared__ alignas(16) bf16 Bs[2][128 * 32];
    const bf16* Ab = A + (long)blockIdx.z * sA;
    const bf16* Bb = Bt + (long)blockIdx.z * sB;
    bf16* Cb = C + (long)blockIdx.z * sC;
    int tid = threadIdx.x;
    int lane = tid & 63, ww = tid >> 6;
    int wm = ww >> 1, wn = ww & 1;
    int quad = lane >> 4, l16 = lane & 15;
    int qx = quad ^ ((l16 >> 1) & 3);
    int sseg = (tid & 3) ^ ((tid >> 3) & 3);
    int m0 = blockIdx.x * 128, n0 = blockIdx.y * 128;
    f32x4 acc[4][4] = {};
    auto STAGE = [&](int k0, int buf) {
#pragma unroll
        for (int i = 0; i < 2; i++) {
            int idx = tid + i * 256;
            int row = idx >> 2;
            async16(&Ab[(long)(m0 + row) * K + k0 + sseg * 8], &As[buf][idx * 8]);
            async16(&Bb[(long)(n0 + row) * K + k0 + sseg * 8], &Bs[buf][idx * 8]);
        }
    };
    int nk = K / 32;   // even for all call sites
    STAGE(0, 0);
    for (int s = 0; s < nk; s += 2) {
#pragma unroll
        for (int u = 0; u < 2; u++) {
            int step = s + u;
            if (step + 1 < nk) STAGE((step + 1) * 32, u ^ 1);
            if (step + 1 < nk) asm volatile("s_waitcnt vmcnt(4)" ::: "memory");
            else               asm volatile("s_waitcnt vmcnt(0)" ::: "memory");
            __builtin_amdgcn_s_barrier();
            __builtin_amdgcn_sched_barrier(0);
            __builtin_amdgcn_s_setprio(1);
            bf16x8 af[4], bfr[4];
#pragma unroll
            for (int mi = 0; mi < 4; mi++)
                af[mi] = *(const bf16x8*)(&As[u][(wm * 64 + mi * 16 + l16) * 32 + qx * 8]);
#pragma unroll
            for (int ni = 0; ni < 4; ni++)
                bfr[ni] = *(const bf16x8*)(&Bs[u][(wn * 64 + ni * 16 + l16) * 32 + qx * 8]);
#pragma unroll
            for (int mi = 0; mi < 4; mi++)
#pragma unroll
                for (int ni = 0; ni < 4; ni++)
                    acc[mi][ni] = __builtin_amdgcn_mfma_f32_16x16x32_bf16(
                        af[mi], bfr[ni], acc[mi][ni], 0, 0, 0);
            __builtin_amdgcn_s_setprio(0);
            __builtin_amdgcn_sched_barrier(0);
            __builtin_amdgcn_s_barrier();
            __builtin_amdgcn_sched_barrier(0);
        }
    }
    for (int mi = 0; mi < 4; mi++)
        for (int ni = 0; ni < 4; ni++) {
            int col = n0 + wn * 64 + ni * 16 + l16;
            for (int r = 0; r < 4; r++) {
                int row = m0 + wm * 64 + mi * 16 + quad * 4 + r;
                Cb[(long)row * Nn + col] = f2bf(acc[mi][ni][r]);
            }
        }
}

// ---------------- PV GEMM with fused per-chunk softmax rescale (FA-style) -----
// Pipelined like gemm_bt. XCD-aware block swizzle (T1): 1-D grid of 512; the 4
// n-blocks sharing one P m-panel map to consecutive slots on the SAME XCD.
__global__ __launch_bounds__(256) void gemm_pv(
        const bf16* __restrict__ A, const bf16* __restrict__ Bt,
        bf16* __restrict__ C, const float* __restrict__ rs,
        const float* __restrict__ fin) {
    __shared__ alignas(16) bf16 As[2][128 * 32];
    __shared__ alignas(16) bf16 Bs[2][128 * 32];
    int flat = blockIdx.x;                 // [0,512)
    int xcd = flat & 7, j = flat >> 3;     // round-robin XCD assumption
    int panel = xcd * 16 + (j >> 2);       // [0,128) = (b,m) panel
    int b = panel >> 4;
    int m0 = (panel & 15) * 128;
    int n0 = (j & 3) * 128;
    const bf16* Ab = A + (long)b * NN * NN;
    const bf16* Bb = Bt + (long)b * FIN * NN;
    bf16* Cb = C + (long)b * NN * FIN;
    int tid = threadIdx.x;
    int lane = tid & 63, ww = tid >> 6;
    int wm = ww >> 1, wn = ww & 1;
    int quad = lane >> 4, l16 = lane & 15;
    int qx = quad ^ ((l16 >> 1) & 3);
    int sseg = (tid & 3) ^ ((tid >> 3) & 3);
    f32x4 acc[4][4] = {};
    auto STAGE = [&](int k0, int buf) {
#pragma unroll
        for (int i = 0; i < 2; i++) {
            int idx = tid + i * 256;
            int row = idx >> 2;
            async16(&Ab[(long)(m0 + row) * NN + k0 + sseg * 8], &As[buf][idx * 8]);
            async16(&Bb[(long)(n0 + row) * NN + k0 + sseg * 8], &Bs[buf][idx * 8]);
        }
    };
    const int nk = NN / 32;  // 64
    STAGE(0, 0);
    for (int s = 0; s < nk; s += 2) {
#pragma unroll
        for (int u = 0; u < 2; u++) {
            int step = s + u;
            int k0 = step * 32;
            if (k0 && !(k0 & 127)) {          // entering chunk c: rescale acc
                int c = k0 >> 7;
#pragma unroll
                for (int mi = 0; mi < 4; mi++) {
                    float4 rv = *(const float4*)(&rs[((long)b * 16 + c) * NN
                                                     + m0 + wm * 64 + mi * 16 + quad * 4]);
#pragma unroll
                    for (int ni = 0; ni < 4; ni++) {
                        acc[mi][ni][0] *= rv.x;
                        acc[mi][ni][1] *= rv.y;
                        acc[mi][ni][2] *= rv.z;
                        acc[mi][ni][3] *= rv.w;
                    }
                }
            }
            if (step + 1 < nk) STAGE((step + 1) * 32, u ^ 1);
            if (step + 1 < nk) asm volatile("s_waitcnt vmcnt(4)" ::: "memory");
            else               asm volatile("s_waitcnt vmcnt(0)" ::: "memory");
            __builtin_amdgcn_s_barrier();
            __builtin_amdgcn_sched_barrier(0);
            __builtin_amdgcn_s_setprio(1);
            bf16x8 af[4], bfr[4];
#pragma unroll
            for (int mi = 0; mi < 4; mi++)
                af[mi] = *(const bf16x8*)(&As[u][(wm * 64 + mi * 16 + l16) * 32 + qx * 8]);
#pragma unroll
            for (int ni = 0; ni < 4; ni++)
                bfr[ni] = *(const bf16x8*)(&Bs[u][(wn * 64 + ni * 16 + l16) * 32 + qx * 8]);
#pragma unroll
            for (int mi = 0; mi < 4; mi++)
#pragma unroll
                for (int ni = 0; ni < 4; ni++)
                    acc[mi][ni] = __builtin_amdgcn_mfma_f32_16x16x32_bf16(
                        af[mi], bfr[ni], acc[mi][ni], 0, 0, 0);
            __builtin_amdgcn_s_setprio(0);
            __builtin_amdgcn_sched_barrier(0);
            __builtin_amdgcn_s_barrier();
            __builtin_amdgcn_sched_barrier(0);
        }
    }
    for (int mi = 0; mi < 4; mi++) {
        float4 fv = *(const float4*)(&fin[(long)b * NN + m0 + wm * 64 + mi * 16 + quad * 4]);
        for (int ni = 0; ni < 4; ni++) {
            int col = n0 + wn * 64 + ni * 16 + l16;
            float fvr[4] = { fv.x, fv.y, fv.z, fv.w };
            for (int r = 0; r < 4; r++) {
                int row = m0 + wm * 64 + mi * 16 + quad * 4 + r;
                Cb[(long)row * FIN + col] = f2bf(acc[mi][ni][r] * fvr[r]);
            }
        }
    }
}

// ---------------- Ay[b,n] = (hh+hl)[b,n,:] . a2 ----------------
__global__ void ay_kernel(const bf16* __restrict__ hh, const bf16* __restrict__ hl,
                          const float* __restrict__ a2, float* __restrict__ Ay) {
    int lane = threadIdx.x & 63, w = threadIdx.x >> 6;
    long row = (long)blockIdx.x * 4 + w;
    float p = 0.f;
    for (int i = 0; i < 4; i++) {
        int d = i * 64 + lane;
        p += (bf2f(hh[row * FOUT + d]) + bf2f(hl[row * FOUT + d])) * a2[d];
    }
    for (int off = 32; off; off >>= 1) p += __shfl_xor(p, off);
    if (lane == 0) Ay[row] = p;
}

// ---------------- single score pass: stats + unnormalized P~ (all 8 batches) ----------------
// r8/r11-verbatim (proven best: 92.4-93.6us, VGPR 120, FETCH 78MB, conflicts 0).
// Schedule arc CLOSED: depth-1/2-buffer optimal (M_rep=2 r4/r7, 1-barrier r5,
// depth-3 r9 refuted). XCD co-location r12 refuted (latency-bound, TLP covers).
__global__ __launch_bounds__(256) void pass_score(
        const bf16* __restrict__ qh_, const bf16* __restrict__ ql_,
        const bf16* __restrict__ hh_, const bf16* __restrict__ hl_,
        const u64* __restrict__ adjm, const float* __restrict__ Ay,
        float* __restrict__ mpm, float* __restrict__ mpl,
        bf16* __restrict__ P) {
    __shared__ alignas(16) bf16 Hsh[2][128 * 32], Hsl[2][128 * 32];
    __shared__ alignas(16) bf16 pst[4][16 * 64];   // per-wave 16x64 half-tile, swizzled
    int tid = threadIdx.x;
    int lane = tid & 63, w = tid >> 6;
    int quad = lane >> 4, l16 = lane & 15;
    int qx = quad ^ ((l16 >> 1) & 3);            // swizzled read segment
    int sseg = (tid & 3) ^ ((tid >> 3) & 3);     // swizzled source segment (staging)
    int b = blockIdx.z, jz = blockIdx.y;
    int i0 = blockIdx.x * 64 + w * 16;
    long qoff = ((long)b * NN + i0) * FOUT;
    const bf16* hbh = hh_ + ((long)b * NN + (long)jz * JW) * FOUT;
    const bf16* hbl = hl_ + ((long)b * NN + (long)jz * JW) * FOUT;
    const u64* amb = adjm + ((long)b * NN + i0) * (NN / 64) + jz * (JW / 64);
    bf16* pw = pst[w];

    bf16x8 qfh[8], qfl[8];
#pragma unroll
    for (int kk = 0; kk < 8; kk++) {
        qfh[kk] = *(const bf16x8*)(&qh_[qoff + (long)l16 * FOUT + kk * 32 + quad * 8]);
        qfl[kk] = *(const bf16x8*)(&ql_[qoff + (long)l16 * FOUT + kk * 32 + quad * 8]);
    }
    float ay_[4];
#pragma unroll
    for (int r = 0; r < 4; r++) ay_[r] = Ay[(long)b * NN + i0 + quad * 4 + r];

    float m_[4], l_[4];
#pragma unroll
    for (int r = 0; r < 4; r++) { m_[r] = -3.0e38f; l_[r] = 0.f; }

    // stage (jc,kk) into buffer `buf`: 4 global_load_lds/thread (source-swizzled)
    auto STAGE = [&](int jc, int kk, int buf) {
#pragma unroll
        for (int i = 0; i < 2; i++) {
            int idx = tid + i * 256;
            int row = idx >> 2;
            long go = (long)(jc * 128 + row) * FOUT + kk * 32 + sseg * 8;
            async16(&hbh[go], &Hsh[buf][idx * 8]);
            async16(&hbl[go], &Hsl[buf][idx * 8]);
        }
    };

    f32x4 sacc[8];
#pragma unroll
    for (int ni = 0; ni < 8; ni++) sacc[ni] = (f32x4){0.f, 0.f, 0.f, 0.f};

    STAGE(0, 0, 0);
    for (int jc = 0; jc < 4; jc++) {          // runtime loop (uniform)
#pragma unroll
        for (int kk = 0; kk < 8; kk++) {      // compile-time: qfh[kk] stays in VGPRs
            const int cur = kk & 1;           // jc*8 is even -> buf parity = kk&1
            // prefetch next step into the other buffer
            if (kk < 7)           STAGE(jc, kk + 1, cur ^ 1);
            else if (jc < 3)      STAGE(jc + 1, 0, cur ^ 1);
            // wait until STAGE(jc,kk) landed; keep newest prefetch in flight
            if (kk == 0) {
                if (jc == 0) asm volatile("s_waitcnt vmcnt(4)" ::: "memory");
                else         asm volatile("s_waitcnt vmcnt(8)" ::: "memory");
            } else if (kk == 7 && jc == 3) {
                asm volatile("s_waitcnt vmcnt(0)" ::: "memory");
            } else {
                asm volatile("s_waitcnt vmcnt(4)" ::: "memory");
            }
            __builtin_amdgcn_s_barrier();     // buf[cur] staged for all waves
            __builtin_amdgcn_sched_barrier(0);

            __builtin_amdgcn_s_setprio(1);
#pragma unroll
            for (int ni = 0; ni < 8; ni++) {
                int so = (ni * 16 + l16) * 32 + qx * 8;
                bf16x8 hfh = *(const bf16x8*)(&Hsh[cur][so]);
                bf16x8 hfl = *(const bf16x8*)(&Hsl[cur][so]);
                sacc[ni] = __builtin_amdgcn_mfma_f32_16x16x32_bf16(qfh[kk], hfh, sacc[ni], 0, 0, 0);
                sacc[ni] = __builtin_amdgcn_mfma_f32_16x16x32_bf16(qfh[kk], hfl, sacc[ni], 0, 0, 0);
                sacc[ni] = __builtin_amdgcn_mfma_f32_16x16x32_bf16(qfl[kk], hfh, sacc[ni], 0, 0, 0);
            }
            __builtin_amdgcn_s_setprio(0);

            if (kk == 7) {
                // ---- epilogue for this jc: mask + leaky relu + online softmax ----
                u64 am[4][2];
#pragma unroll
                for (int r = 0; r < 4; r++) {
                    am[r][0] = amb[(long)(quad * 4 + r) * (NN / 64) + jc * 2 + 0];
                    am[r][1] = amb[(long)(quad * 4 + r) * (NN / 64) + jc * 2 + 1];
                }
#pragma unroll
                for (int ni = 0; ni < 8; ni++)
#pragma unroll
                    for (int r = 0; r < 4; r++) {
                        float v = sacc[ni][r] + ay_[r];
                        v = v > 0.f ? v : ALPHA_ * v;
                        int bit = (int)((am[r][ni >> 2] >> ((ni * 16 + l16) & 63)) & 1);
                        sacc[ni][r] = bit ? v : NEGV;
                    }
#pragma unroll
                for (int r = 0; r < 4; r++) {
                    float mc = -3.0e38f;
#pragma unroll
                    for (int ni = 0; ni < 8; ni++) mc = fmaxf(mc, sacc[ni][r]);
                    for (int off = 8; off; off >>= 1) mc = fmaxf(mc, __shfl_xor(mc, off));
                    float mnew = fmaxf(m_[r], mc);
                    float scale = __expf(m_[r] - mnew);
                    float ps = 0.f;
#pragma unroll
                    for (int ni = 0; ni < 8; ni++) {
                        float p = __expf(sacc[ni][r] - mnew);
                        sacc[ni][r] = p;
                        ps += p;
                    }
                    for (int off = 8; off; off >>= 1) ps += __shfl_xor(ps, off);
                    l_[r] = l_[r] * scale + ps;
                    m_[r] = mnew;
                    if (l16 == 0)
                        mpm[(((long)b * 4 + jz) * 4 + jc) * NN + i0 + quad * 4 + r] = mnew;
                }
                // ---- P~ store via swizzled per-wave LDS half-tiles (2 rounds) ----
#pragma unroll
                for (int h = 0; h < 2; h++) {
#pragma unroll
                    for (int ni = 0; ni < 4; ni++)
#pragma unroll
                        for (int r = 0; r < 4; r++) {
                            int row = quad * 4 + r;
                            int byt = (row * 128 + (ni * 16 + l16) * 2) ^ ((row & 7) << 4);
                            *(bf16*)((char*)pw + byt) = f2bf(sacc[h * 4 + ni][r]);
                        }
#pragma unroll
                    for (int s2 = 0; s2 < 2; s2++) {
                        int cq = quad + s2 * 4;
                        int byt = (l16 * 128 + cq * 16) ^ ((l16 & 7) << 4);
                        uint4 v = *(const uint4*)((const char*)pw + byt);
                        *(uint4*)(&P[((long)b * NN + i0 + l16) * NN + (long)jz * JW
                                     + jc * 128 + h * 64 + cq * 8]) = v;
                    }
                }
#pragma unroll
                for (int ni = 0; ni < 8; ni++) sacc[ni] = (f32x4){0.f, 0.f, 0.f, 0.f};
            }
            __builtin_amdgcn_sched_barrier(0);
            __builtin_amdgcn_s_barrier();   // all waves done reading buf[cur] before restage
            __builtin_amdgcn_sched_barrier(0);
        }
    }
    if (l16 == 0)
#pragma unroll
        for (int r = 0; r < 4; r++)
            mpl[((long)b * 4 + jz) * NN + i0 + quad * 4 + r] = l_[r];
}

// ---------------- merge window stats -> chunk ratios rs + final scale fin ----------------
// rs[b,c,n] = exp(m_{c-1} - m_c)  (c=1..15; c=0 unused)
// fin[b,n]  = exp(m_15 - m_glob) / l_glob
__global__ void ml_merge(const float* __restrict__ mpm, const float* __restrict__ mpl,
                         float* __restrict__ rs, float* __restrict__ fin) {
    long row = (long)blockIdx.x * blockDim.x + threadIdx.x;  // [0, BB*NN)
    long b = row / NN, n = row % NN;
    float mc[16];
#pragma unroll
    for (int c = 0; c < 16; c++) mc[c] = mpm[(b * 16 + c) * NN + n];
    float m = fmaxf(fmaxf(mc[3], mc[7]), fmaxf(mc[11], mc[15]));
    float l = 0.f;
#pragma unroll
    for (int jz = 0; jz < 4; jz++)
        l += mpl[(b * 4 + jz) * NN + n] * __expf(mc[jz * 4 + 3] - m);
    fin[row] = __expf(mc[15] - m) / l;
#pragma unroll
    for (int c = 1; c < 16; c++)
        rs[(b * 16 + c) * NN + n] = __expf(mc[c - 1] - mc[c]);
}

// ---------------- e = X_bf16[*,512] @ W_f32[5,512]^T (fp32 out) ----------------
__global__ void e_kernel(const bf16* __restrict__ X, const float* __restrict__ Wt,
                         float* __restrict__ out) {
    int lane = threadIdx.x & 63, w = threadIdx.x >> 6;
    long row = (long)blockIdx.x * 4 + w;
    uint4 raw = *(const uint4*)(&X[row * FIN + lane * 8]);
    const bf16* xp = (const bf16*)&raw;
    float xv[8];
    for (int i = 0; i < 8; i++) xv[i] = bf2f(xp[i]);
    for (int e = 0; e < EE; e++) {
        float4 w0 = *(const float4*)(&Wt[e * FIN + lane * 8]);
        float4 w1 = *(const float4*)(&Wt[e * FIN + lane * 8 + 4]);
        float p = xv[0] * w0.x + xv[1] * w0.y + xv[2] * w0.z + xv[3] * w0.w
                + xv[4] * w1.x + xv[5] * w1.y + xv[6] * w1.z + xv[7] * w1.w;
        for (int off = 32; off; off >>= 1) p += __shfl_xor(p, off);
        if (lane == 0) out[row * EE + e] = p;
    }
}

// ---------------- out(fp32) = h1 + h2 + e1.Bw.e2 ----------------
__global__ void final_kernel(float* __restrict__ out,
                             const bf16* __restrict__ h1, const bf16* __restrict__ h2,
                             const float* __restrict__ e1, const float* __restrict__ e2,
                             const float* __restrict__ Bw) {
    long row = blockIdx.x;
    int o = threadIdx.x;
    float a[EE], c[EE];
    for (int i = 0; i < EE; i++) { a[i] = e1[row * EE + i]; c[i] = e2[row * EE + i]; }
    const float* bw = Bw + (long)o * EE * EE;
    float acc = 0.f;
    for (int i = 0; i < EE; i++)
        for (int j = 0; j < EE; j++)
            acc += bw[i * EE + j] * a[i] * c[j];
    long idx = row * FOUT + o;
    out[idx] = acc + bf2f(h1[idx]) + bf2f(h2[idx]);
}

extern "C" void kernel_launch(void* const* d_in, const int* in_sizes, int n_in,
                              void* d_out, int out_size, void* d_ws, size_t ws_size,
                              hipStream_t stream) {
    const float* feat = (const float*)d_in[0];
    const int*   adj  = (const int*)d_in[1];
    const float* W    = (const float*)d_in[2];
    const float* W1   = (const float*)d_in[3];
    const float* W2   = (const float*)d_in[4];
    const float* a1   = (const float*)d_in[5];
    const float* a2   = (const float*)d_in[6];
    const float* a12  = (const float*)d_in[7];
    const float* Lw   = (const float*)d_in[8];
    const float* Rw   = (const float*)d_in[9];
    const float* Bw   = (const float*)d_in[10];
    float* out = (float*)d_out;

    char* ws = (char*)d_ws;
    size_t off = 0;
    auto alloc = [&](size_t bytes) {
        char* p = ws + off;
        off += (bytes + 255) & ~(size_t)255;
        return p;
    };
    bf16* WTh  = (bf16*)alloc((size_t)FOUT * FIN * 2);
    bf16* WTl  = (bf16*)alloc((size_t)FOUT * FIN * 2);
    bf16* W1T  = (bf16*)alloc((size_t)FOUT * FIN * 2);
    bf16* W2T  = (bf16*)alloc((size_t)FOUT * FIN * 2);
    bf16* aTh  = (bf16*)alloc((size_t)FOUT * FOUT * 2);
    bf16* aTl  = (bf16*)alloc((size_t)FOUT * FOUT * 2);
    bf16* fh   = (bf16*)alloc((size_t)BB * NN * FIN * 2);     // 16.8 MB
    bf16* fl   = (bf16*)alloc((size_t)BB * NN * FIN * 2);     // 16.8 MB (fagg later)
    bf16* hh   = (bf16*)alloc((size_t)BB * NN * FOUT * 2);    // 8.4 MB (h1 later)
    bf16* hl   = (bf16*)alloc((size_t)BB * NN * FOUT * 2);    // 8.4 MB (h2 later)
    bf16* featT= (bf16*)alloc((size_t)BB * NN * FIN * 2);     // 16.8 MB
    float* Ay  = (float*)alloc((size_t)BB * NN * 4);
    float* mpm = (float*)alloc((size_t)BB * 4 * 4 * NN * 4);  // 1 MB
    float* mpl = (float*)alloc((size_t)BB * 4 * NN * 4);      // 256 KB
    float* rs  = (float*)alloc((size_t)BB * 16 * NN * 4);     // 2 MB chunk ratios
    float* fin = (float*)alloc((size_t)BB * NN * 4);          // 64 KB final scales
    float* e1  = (float*)alloc((size_t)BB * NN * EE * 4);
    float* e2  = (float*)alloc((size_t)BB * NN * EE * 4);
    u64* adjm  = (u64*)alloc((size_t)BB * NN * (NN / 64) * 8);// 4.2 MB
    bf16* P    = (bf16*)alloc((size_t)BB * NN * NN * 2);      // 67.1 MB (all batches)
    // aliases (lifetimes disjoint):  peak ws ~140 MB (ws is ~512 MB)
    bf16* qh   = (bf16*)d_out;                          // q pair in out (16.8 MB)
    bf16* ql   = qh + (size_t)BB * NN * FOUT;
    bf16* fagg = fl;                                    // fl dead after h-GEMM
    bf16* h1   = hh;                                    // h pair dead after scores
    bf16* h2   = hl;

    dim3 tb(32, 8, 1);
    // input conversions
    split_f32_bf16<<<(BB * NN * FIN) / (256 * 8), 256, 0, stream>>>(feat, fh, fl);
    pack_adj<<<(BB * NN * NN) / (256 * 4), 256, 0, stream>>>(adj, adjm);
    transpose_split<<<dim3(FOUT / 32, FIN / 32, 1), tb, 0, stream>>>(W, WTh, WTl, FIN, FOUT);
    transpose_split<<<dim3(FOUT / 32, FOUT / 32, 1), tb, 0, stream>>>(a12, aTh, aTl, FOUT, FOUT);
    transpose_f32_bf16<<<dim3(FOUT / 32, FIN / 32, 1), tb, 0, stream>>>(W1, W1T, FIN, FOUT, 0, 0);
    transpose_f32_bf16<<<dim3(FOUT / 32, FIN / 32, 1), tb, 0, stream>>>(W2, W2T, FIN, FOUT, 0, 0);
    transpose_f32_bf16<<<dim3(FIN / 32, NN / 32, BB), tb, 0, stream>>>(
        feat, featT, NN, FIN, (long)NN * FIN, (long)FIN * NN);
    // h = feat @ W   (split precision)
    gemm_bt_split<<<dim3(BB * NN / 128, FOUT / 128, 1), 256, 0, stream>>>(
        fh, fl, WTh, WTl, hh, hl, nullptr, FOUT, FIN);
    // Ay = h @ a2
    ay_kernel<<<BB * NN / 4, 256, 0, stream>>>(hh, hl, a2, Ay);
    // q = h @ a12 + a1   (folds Ax[j] into q.h)
    gemm_bt_split<<<dim3(BB * NN / 128, FOUT / 128, 1), 256, 0, stream>>>(
        hh, hl, aTh, aTl, qh, ql, a1, FOUT, FOUT);
    // attention: scores+P~ -> merge -> fused-rescale PV  (no fixup pass)
    pass_score<<<dim3(NN / 64, 4, BB), 256, 0, stream>>>(
        qh, ql, hh, hl, adjm, Ay, mpm, mpl, P);
    ml_merge<<<(BB * NN) / 256, 256, 0, stream>>>(mpm, mpl, rs, fin);
    gemm_pv<<<dim3(512, 1, 1), 256, 0, stream>>>(
        P, featT, fagg, rs, fin);
    // h1 = feat @ W1 ; h2 = fagg @ W2
    gemm_bt<<<dim3(BB * NN / 128, FOUT / 128, 1), 256, 0, stream>>>(
        fh, W1T, h1, FOUT, FIN, 0, 0, 0);
    gemm_bt<<<dim3(BB * NN / 128, FOUT / 128, 1), 256, 0, stream>>>(
        fagg, W2T, h2, FOUT, FIN, 0, 0, 0);
    // e1 = feat @ Lw^T ; e2 = fagg @ Rw^T
    e_kernel<<<BB * NN / 4, 256, 0, stream>>>(fh, Lw, e1);
    e_kernel<<<BB * NN / 4, 256, 0, stream>>>(fagg, Rw, e2);
    // out = h1 + h2 + e1.Bw.e2
    final_kernel<<<BB * NN, FOUT, 0, stream>>>(out, h1, h2, e1, e2, Bw);
}

// Round 15
// 513.104 us; speedup vs baseline: 1.0305x; 1.0123x over previous
//
#include <hip/hip_runtime.h>
#include <hip/hip_bf16.h>

#define BB 8
#define NN 2048
#define FIN 512
#define FOUT 256
#define EE 5
#define ALPHA_ 0.2f
#define NEGV -9e15f
#define JW 512   // j-window per jz

typedef __hip_bfloat16 bf16;
typedef __bf16 bf16x8 __attribute__((ext_vector_type(8)));
typedef float f32x4 __attribute__((ext_vector_type(4)));
typedef unsigned long long u64;

__device__ __forceinline__ float bf2f(bf16 x) { return __bfloat162float(x); }
__device__ __forceinline__ bf16 f2bf(float x) { return __float2bfloat16(x); }

// async global->LDS, 16B per lane. LDS dest must be wave-uniform base + lane*16
// (true for all call sites: lds offset == idx*16B with idx = tid [+ i*256]).
__device__ __forceinline__ void async16(const bf16* g, bf16* l) {
    __builtin_amdgcn_global_load_lds(
        (const __attribute__((address_space(1))) void*)g,
        (__attribute__((address_space(3))) void*)l, 16, 0, 0);
}

// LDS tile swizzle (both-sides transform, rule #21): tiles are [row][32] bf16 =
// row stride 64B; fragment reads at row*64 + quad*16 are an 8-way bank conflict.
// Permute the four 16B segments per row by seg ^= (row>>1)&3 on BOTH the global
// source (staging) and the LDS read offset. 8-way -> 2-way (free). Verified r3:
// SQ_LDS_BANK_CONFLICT = 0. Formulas invariant under 64-row tiles (offsets all
// multiples of 8 rows).
//
// Pipelined GEMM schedule (proven r0->r3/r8/r11): double-buffered LDS, prefetch
// before wait, counted s_waitcnt vmcnt(N) (never 0 mid-loop) + raw s_barrier,
// setprio(1) around MFMA. Buffer parity COMPILE-TIME (r5 lesson).
// r15 change: gemm_bt / gemm_bt_split retiled 128x128 -> 64x128. Their grids
// were 256 blocks = 1 block/CU = 1 wave/SIMD -- ZERO cross-wave latency hiding
// (this family is TLP-bound: r9 showed perf tracks occupancy linearly). 64-row
// tiles double the grid to 512 = 2 blocks/CU. Extra B-tile reads are free (B =
// weight matrices, L2-resident). pass_score / gemm_pv unchanged.

// ---------------- split fp32 -> bf16 (hi, lo), flat, 8/thread ----------------
__global__ void split_f32_bf16(const float* __restrict__ in,
                               bf16* __restrict__ hi, bf16* __restrict__ lo) {
    long i = ((long)blockIdx.x * blockDim.x + threadIdx.x) * 8;
    float4 a = *(const float4*)(&in[i]);
    float4 b = *(const float4*)(&in[i + 4]);
    float x[8] = { a.x, a.y, a.z, a.w, b.x, b.y, b.z, b.w };
    bf16 th[8], tl[8];
    for (int k = 0; k < 8; k++) {
        th[k] = f2bf(x[k]);
        tl[k] = f2bf(x[k] - bf2f(th[k]));
    }
    *(uint4*)(&hi[i]) = *(const uint4*)th;
    *(uint4*)(&lo[i]) = *(const uint4*)tl;
}

// ---------------- pack adj (int32 > 0) into 64-col bitmasks ----------------
__global__ void pack_adj(const int* __restrict__ adj, u64* __restrict__ adjm) {
    long wid = (((long)blockIdx.x * 256) + threadIdx.x) >> 6;
    int lane = threadIdx.x & 63;
    long base = wid * 256;
    for (int c = 0; c < 4; c++) {
        int a = adj[base + c * 64 + lane];
        u64 m = __ballot(a > 0);
        if (lane == 0) adjm[base / 64 + c] = m;
    }
}

// ---------------- transpose+split: fp32 [R,C] -> bf16 hi/lo [C,R] ----------------
__global__ void transpose_split(const float* __restrict__ in,
                                bf16* __restrict__ hi, bf16* __restrict__ lo,
                                int R, int C) {
    __shared__ bf16 th[32][33], tl[32][33];
    int c0 = blockIdx.x * 32, r0 = blockIdx.y * 32;
    int x = threadIdx.x, y = threadIdx.y;  // 32 x 8
    for (int k = 0; k < 4; k++) {
        int r = y + k * 8;
        float f = in[(long)(r0 + r) * C + c0 + x];
        bf16 h = f2bf(f);
        th[r][x] = h;
        tl[r][x] = f2bf(f - bf2f(h));
    }
    __syncthreads();
    for (int k = 0; k < 4; k++) {
        int r = y + k * 8;
        hi[(long)(c0 + r) * R + r0 + x] = th[x][r];
        lo[(long)(c0 + r) * R + r0 + x] = tl[x][r];
    }
}

// ---------------- transpose + convert: fp32 [R,C] -> bf16 [C,R] ----------------
__global__ void transpose_f32_bf16(const float* __restrict__ in, bf16* __restrict__ out,
                                   int R, int C, long sin_b, long sout_b) {
    __shared__ bf16 tile[32][33];
    long bi = (long)blockIdx.z * sin_b;
    long bo = (long)blockIdx.z * sout_b;
    int c0 = blockIdx.x * 32, r0 = blockIdx.y * 32;
    int x = threadIdx.x, y = threadIdx.y;
    for (int k = 0; k < 4; k++) {
        int r = y + k * 8;
        tile[r][x] = f2bf(in[bi + (long)(r0 + r) * C + c0 + x]);
    }
    __syncthreads();
    for (int k = 0; k < 4; k++) {
        int r = y + k * 8;
        out[bo + (long)(c0 + r) * R + r0 + x] = tile[x][r];
    }
}

// ---------------- split GEMM 64x128: C = (Ah+Al)[M,K] @ (Bh+Bl)[N,K]^T + bias --
// r15: 64-row M-tile (grid 2x -> 2 blocks/CU). 4 waves as 2x2, each 32x64,
// acc[2][4]. 6 loads/step (A h+l 1 each, B h+l 2 each) -> steady vmcnt(6).
__global__ __launch_bounds__(256) void gemm_bt_split(
        const bf16* __restrict__ Ah, const bf16* __restrict__ Al,
        const bf16* __restrict__ Bh, const bf16* __restrict__ Bl,
        bf16* __restrict__ Chi, bf16* __restrict__ Clo,
        const float* __restrict__ bias, int Nn, int K) {
    __shared__ alignas(16) bf16 Ash[2][64 * 32], Asl[2][64 * 32];
    __shared__ alignas(16) bf16 Bsh[2][128 * 32], Bsl[2][128 * 32];
    int tid = threadIdx.x;
    int lane = tid & 63, ww = tid >> 6;
    int wm = ww >> 1, wn = ww & 1;
    int quad = lane >> 4, l16 = lane & 15;
    int qx = quad ^ ((l16 >> 1) & 3);            // swizzled read segment
    int sseg = (tid & 3) ^ ((tid >> 3) & 3);     // swizzled source segment (staging)
    int m0 = blockIdx.x * 64, n0 = blockIdx.y * 128;
    f32x4 acc[2][4] = {};
    auto STAGE = [&](int k0, int buf) {
        {   // A: 64 rows, 1 load/thread (x2 for h/l)
            int row = tid >> 2;
            long ao = (long)(m0 + row) * K + k0 + sseg * 8;
            async16(&Ah[ao], &Ash[buf][tid * 8]);
            async16(&Al[ao], &Asl[buf][tid * 8]);
        }
#pragma unroll
        for (int i = 0; i < 2; i++) {   // B: 128 rows, 2 loads/thread (x2)
            int idx = tid + i * 256;
            int row = idx >> 2;
            long bo = (long)(n0 + row) * K + k0 + sseg * 8;
            async16(&Bh[bo], &Bsh[buf][idx * 8]);
            async16(&Bl[bo], &Bsl[buf][idx * 8]);
        }
    };
    int nk = K / 32;   // even for all call sites (16 or 8)
    STAGE(0, 0);
    for (int s = 0; s < nk; s += 2) {
#pragma unroll
        for (int u = 0; u < 2; u++) {            // compile-time buffer parity
            int step = s + u;
            if (step + 1 < nk) STAGE((step + 1) * 32, u ^ 1);
            if (step + 1 < nk) asm volatile("s_waitcnt vmcnt(6)" ::: "memory");
            else               asm volatile("s_waitcnt vmcnt(0)" ::: "memory");
            __builtin_amdgcn_s_barrier();
            __builtin_amdgcn_sched_barrier(0);
            __builtin_amdgcn_s_setprio(1);
            bf16x8 afh[2], afl[2], bfh[4], bfl[4];
#pragma unroll
            for (int mi = 0; mi < 2; mi++) {
                int so = (wm * 32 + mi * 16 + l16) * 32 + qx * 8;
                afh[mi] = *(const bf16x8*)(&Ash[u][so]);
                afl[mi] = *(const bf16x8*)(&Asl[u][so]);
            }
#pragma unroll
            for (int ni = 0; ni < 4; ni++) {
                int so = (wn * 64 + ni * 16 + l16) * 32 + qx * 8;
                bfh[ni] = *(const bf16x8*)(&Bsh[u][so]);
                bfl[ni] = *(const bf16x8*)(&Bsl[u][so]);
            }
#pragma unroll
            for (int mi = 0; mi < 2; mi++)
#pragma unroll
                for (int ni = 0; ni < 4; ni++) {
                    acc[mi][ni] = __builtin_amdgcn_mfma_f32_16x16x32_bf16(afh[mi], bfh[ni], acc[mi][ni], 0, 0, 0);
                    acc[mi][ni] = __builtin_amdgcn_mfma_f32_16x16x32_bf16(afh[mi], bfl[ni], acc[mi][ni], 0, 0, 0);
                    acc[mi][ni] = __builtin_amdgcn_mfma_f32_16x16x32_bf16(afl[mi], bfh[ni], acc[mi][ni], 0, 0, 0);
                }
            __builtin_amdgcn_s_setprio(0);
            __builtin_amdgcn_sched_barrier(0);
            __builtin_amdgcn_s_barrier();        // readers done before buf[u] restaged
            __builtin_amdgcn_sched_barrier(0);
        }
    }
    for (int mi = 0; mi < 2; mi++)
        for (int ni = 0; ni < 4; ni++) {
            int col = n0 + wn * 64 + ni * 16 + l16;
            float bv = bias ? bias[col] : 0.f;
            for (int r = 0; r < 4; r++) {
                int row = m0 + wm * 32 + mi * 16 + quad * 4 + r;
                float v = acc[mi][ni][r] + bv;
                bf16 h = f2bf(v);
                Chi[(long)row * Nn + col] = h;
                Clo[(long)row * Nn + col] = f2bf(v - bf2f(h));
            }
        }
}

// ---------------- plain bf16 GEMM 64x128: C[M,N] = A[M,K] @ Bt[N,K]^T ----------
// r15: 64-row M-tile (grid 2x -> 2 blocks/CU). acc[2][4]. 3 loads/step ->
// steady vmcnt(3).
__global__ __launch_bounds__(256) void gemm_bt(
        const bf16* __restrict__ A, const bf16* __restrict__ Bt,
        bf16* __restrict__ C, int Nn, int K, long sA, long sB, long sC) {
    __shared__ alignas(16) bf16 As[2][64 * 32];
    __shared__ alignas(16) bf16 Bs[2][128 * 32];
    const bf16* Ab = A + (long)blockIdx.z * sA;
    const bf16* Bb = Bt + (long)blockIdx.z * sB;
    bf16* Cb = C + (long)blockIdx.z * sC;
    int tid = threadIdx.x;
    int lane = tid & 63, ww = tid >> 6;
    int wm = ww >> 1, wn = ww & 1;
    int quad = lane >> 4, l16 = lane & 15;
    int qx = quad ^ ((l16 >> 1) & 3);
    int sseg = (tid & 3) ^ ((tid >> 3) & 3);
    int m0 = blockIdx.x * 64, n0 = blockIdx.y * 128;
    f32x4 acc[2][4] = {};
    auto STAGE = [&](int k0, int buf) {
        {
            int row = tid >> 2;
            async16(&Ab[(long)(m0 + row) * K + k0 + sseg * 8], &As[buf][tid * 8]);
        }
#pragma unroll
        for (int i = 0; i < 2; i++) {
            int idx = tid + i * 256;
            int row = idx >> 2;
            async16(&Bb[(long)(n0 + row) * K + k0 + sseg * 8], &Bs[buf][idx * 8]);
        }
    };
    int nk = K / 32;   // even for all call sites
    STAGE(0, 0);
    for (int s = 0; s < nk; s += 2) {
#pragma unroll
        for (int u = 0; u < 2; u++) {
            int step = s + u;
            if (step + 1 < nk) STAGE((step + 1) * 32, u ^ 1);
            if (step + 1 < nk) asm volatile("s_waitcnt vmcnt(3)" ::: "memory");
            else               asm volatile("s_waitcnt vmcnt(0)" ::: "memory");
            __builtin_amdgcn_s_barrier();
            __builtin_amdgcn_sched_barrier(0);
            __builtin_amdgcn_s_setprio(1);
            bf16x8 af[2], bfr[4];
#pragma unroll
            for (int mi = 0; mi < 2; mi++)
                af[mi] = *(const bf16x8*)(&As[u][(wm * 32 + mi * 16 + l16) * 32 + qx * 8]);
#pragma unroll
            for (int ni = 0; ni < 4; ni++)
                bfr[ni] = *(const bf16x8*)(&Bs[u][(wn * 64 + ni * 16 + l16) * 32 + qx * 8]);
#pragma unroll
            for (int mi = 0; mi < 2; mi++)
#pragma unroll
                for (int ni = 0; ni < 4; ni++)
                    acc[mi][ni] = __builtin_amdgcn_mfma_f32_16x16x32_bf16(
                        af[mi], bfr[ni], acc[mi][ni], 0, 0, 0);
            __builtin_amdgcn_s_setprio(0);
            __builtin_amdgcn_sched_barrier(0);
            __builtin_amdgcn_s_barrier();
            __builtin_amdgcn_sched_barrier(0);
        }
    }
    for (int mi = 0; mi < 2; mi++)
        for (int ni = 0; ni < 4; ni++) {
            int col = n0 + wn * 64 + ni * 16 + l16;
            for (int r = 0; r < 4; r++) {
                int row = m0 + wm * 32 + mi * 16 + quad * 4 + r;
                Cb[(long)row * Nn + col] = f2bf(acc[mi][ni][r]);
            }
        }
}

// ---------------- PV GEMM with fused per-chunk softmax rescale (FA-style) -----
// Pipelined 128x128 (K=2048, grid already 2 blocks/CU). XCD-aware swizzle (T1).
__global__ __launch_bounds__(256) void gemm_pv(
        const bf16* __restrict__ A, const bf16* __restrict__ Bt,
        bf16* __restrict__ C, const float* __restrict__ rs,
        const float* __restrict__ fin) {
    __shared__ alignas(16) bf16 As[2][128 * 32];
    __shared__ alignas(16) bf16 Bs[2][128 * 32];
    int flat = blockIdx.x;                 // [0,512)
    int xcd = flat & 7, j = flat >> 3;     // round-robin XCD assumption
    int panel = xcd * 16 + (j >> 2);       // [0,128) = (b,m) panel
    int b = panel >> 4;
    int m0 = (panel & 15) * 128;
    int n0 = (j & 3) * 128;
    const bf16* Ab = A + (long)b * NN * NN;
    const bf16* Bb = Bt + (long)b * FIN * NN;
    bf16* Cb = C + (long)b * NN * FIN;
    int tid = threadIdx.x;
    int lane = tid & 63, ww = tid >> 6;
    int wm = ww >> 1, wn = ww & 1;
    int quad = lane >> 4, l16 = lane & 15;
    int qx = quad ^ ((l16 >> 1) & 3);
    int sseg = (tid & 3) ^ ((tid >> 3) & 3);
    f32x4 acc[4][4] = {};
    auto STAGE = [&](int k0, int buf) {
#pragma unroll
        for (int i = 0; i < 2; i++) {
            int idx = tid + i * 256;
            int row = idx >> 2;
            async16(&Ab[(long)(m0 + row) * NN + k0 + sseg * 8], &As[buf][idx * 8]);
            async16(&Bb[(long)(n0 + row) * NN + k0 + sseg * 8], &Bs[buf][idx * 8]);
        }
    };
    const int nk = NN / 32;  // 64
    STAGE(0, 0);
    for (int s = 0; s < nk; s += 2) {
#pragma unroll
        for (int u = 0; u < 2; u++) {
            int step = s + u;
            int k0 = step * 32;
            if (k0 && !(k0 & 127)) {          // entering chunk c: rescale acc
                int c = k0 >> 7;
#pragma unroll
                for (int mi = 0; mi < 4; mi++) {
                    float4 rv = *(const float4*)(&rs[((long)b * 16 + c) * NN
                                                     + m0 + wm * 64 + mi * 16 + quad * 4]);
#pragma unroll
                    for (int ni = 0; ni < 4; ni++) {
                        acc[mi][ni][0] *= rv.x;
                        acc[mi][ni][1] *= rv.y;
                        acc[mi][ni][2] *= rv.z;
                        acc[mi][ni][3] *= rv.w;
                    }
                }
            }
            if (step + 1 < nk) STAGE((step + 1) * 32, u ^ 1);
            if (step + 1 < nk) asm volatile("s_waitcnt vmcnt(4)" ::: "memory");
            else               asm volatile("s_waitcnt vmcnt(0)" ::: "memory");
            __builtin_amdgcn_s_barrier();
            __builtin_amdgcn_sched_barrier(0);
            __builtin_amdgcn_s_setprio(1);
            bf16x8 af[4], bfr[4];
#pragma unroll
            for (int mi = 0; mi < 4; mi++)
                af[mi] = *(const bf16x8*)(&As[u][(wm * 64 + mi * 16 + l16) * 32 + qx * 8]);
#pragma unroll
            for (int ni = 0; ni < 4; ni++)
                bfr[ni] = *(const bf16x8*)(&Bs[u][(wn * 64 + ni * 16 + l16) * 32 + qx * 8]);
#pragma unroll
            for (int mi = 0; mi < 4; mi++)
#pragma unroll
                for (int ni = 0; ni < 4; ni++)
                    acc[mi][ni] = __builtin_amdgcn_mfma_f32_16x16x32_bf16(
                        af[mi], bfr[ni], acc[mi][ni], 0, 0, 0);
            __builtin_amdgcn_s_setprio(0);
            __builtin_amdgcn_sched_barrier(0);
            __builtin_amdgcn_s_barrier();
            __builtin_amdgcn_sched_barrier(0);
        }
    }
    for (int mi = 0; mi < 4; mi++) {
        float4 fv = *(const float4*)(&fin[(long)b * NN + m0 + wm * 64 + mi * 16 + quad * 4]);
        for (int ni = 0; ni < 4; ni++) {
            int col = n0 + wn * 64 + ni * 16 + l16;
            float fvr[4] = { fv.x, fv.y, fv.z, fv.w };
            for (int r = 0; r < 4; r++) {
                int row = m0 + wm * 64 + mi * 16 + quad * 4 + r;
                Cb[(long)row * FIN + col] = f2bf(acc[mi][ni][r] * fvr[r]);
            }
        }
    }
}

// ---------------- Ay[b,n] = (hh+hl)[b,n,:] . a2 ----------------
__global__ void ay_kernel(const bf16* __restrict__ hh, const bf16* __restrict__ hl,
                          const float* __restrict__ a2, float* __restrict__ Ay) {
    int lane = threadIdx.x & 63, w = threadIdx.x >> 6;
    long row = (long)blockIdx.x * 4 + w;
    float p = 0.f;
    for (int i = 0; i < 4; i++) {
        int d = i * 64 + lane;
        p += (bf2f(hh[row * FOUT + d]) + bf2f(hl[row * FOUT + d])) * a2[d];
    }
    for (int off = 32; off; off >>= 1) p += __shfl_xor(p, off);
    if (lane == 0) Ay[row] = p;
}

// ---------------- single score pass: stats + unnormalized P~ (all 8 batches) ----------------
// r8/r11-verbatim (proven best: 92.4-95.9us, VGPR 120, FETCH 78MB, conflicts 0).
// Schedule arc CLOSED: depth-1/2-buffer optimal (M_rep=2 r4/r7, 1-barrier r5,
// depth-3 r9 refuted). XCD co-location r12 refuted (latency-bound, TLP covers).
__global__ __launch_bounds__(256) void pass_score(
        const bf16* __restrict__ qh_, const bf16* __restrict__ ql_,
        const bf16* __restrict__ hh_, const bf16* __restrict__ hl_,
        const u64* __restrict__ adjm, const float* __restrict__ Ay,
        float* __restrict__ mpm, float* __restrict__ mpl,
        bf16* __restrict__ P) {
    __shared__ alignas(16) bf16 Hsh[2][128 * 32], Hsl[2][128 * 32];
    __shared__ alignas(16) bf16 pst[4][16 * 64];   // per-wave 16x64 half-tile, swizzled
    int tid = threadIdx.x;
    int lane = tid & 63, w = tid >> 6;
    int quad = lane >> 4, l16 = lane & 15;
    int qx = quad ^ ((l16 >> 1) & 3);            // swizzled read segment
    int sseg = (tid & 3) ^ ((tid >> 3) & 3);     // swizzled source segment (staging)
    int b = blockIdx.z, jz = blockIdx.y;
    int i0 = blockIdx.x * 64 + w * 16;
    long qoff = ((long)b * NN + i0) * FOUT;
    const bf16* hbh = hh_ + ((long)b * NN + (long)jz * JW) * FOUT;
    const bf16* hbl = hl_ + ((long)b * NN + (long)jz * JW) * FOUT;
    const u64* amb = adjm + ((long)b * NN + i0) * (NN / 64) + jz * (JW / 64);
    bf16* pw = pst[w];

    bf16x8 qfh[8], qfl[8];
#pragma unroll
    for (int kk = 0; kk < 8; kk++) {
        qfh[kk] = *(const bf16x8*)(&qh_[qoff + (long)l16 * FOUT + kk * 32 + quad * 8]);
        qfl[kk] = *(const bf16x8*)(&ql_[qoff + (long)l16 * FOUT + kk * 32 + quad * 8]);
    }
    float ay_[4];
#pragma unroll
    for (int r = 0; r < 4; r++) ay_[r] = Ay[(long)b * NN + i0 + quad * 4 + r];

    float m_[4], l_[4];
#pragma unroll
    for (int r = 0; r < 4; r++) { m_[r] = -3.0e38f; l_[r] = 0.f; }

    // stage (jc,kk) into buffer `buf`: 4 global_load_lds/thread (source-swizzled)
    auto STAGE = [&](int jc, int kk, int buf) {
#pragma unroll
        for (int i = 0; i < 2; i++) {
            int idx = tid + i * 256;
            int row = idx >> 2;
            long go = (long)(jc * 128 + row) * FOUT + kk * 32 + sseg * 8;
            async16(&hbh[go], &Hsh[buf][idx * 8]);
            async16(&hbl[go], &Hsl[buf][idx * 8]);
        }
    };

    f32x4 sacc[8];
#pragma unroll
    for (int ni = 0; ni < 8; ni++) sacc[ni] = (f32x4){0.f, 0.f, 0.f, 0.f};

    STAGE(0, 0, 0);
    for (int jc = 0; jc < 4; jc++) {          // runtime loop (uniform)
#pragma unroll
        for (int kk = 0; kk < 8; kk++) {      // compile-time: qfh[kk] stays in VGPRs
            const int cur = kk & 1;           // jc*8 is even -> buf parity = kk&1
            // prefetch next step into the other buffer
            if (kk < 7)           STAGE(jc, kk + 1, cur ^ 1);
            else if (jc < 3)      STAGE(jc + 1, 0, cur ^ 1);
            // wait until STAGE(jc,kk) landed; keep newest prefetch in flight
            if (kk == 0) {
                if (jc == 0) asm volatile("s_waitcnt vmcnt(4)" ::: "memory");
                else         asm volatile("s_waitcnt vmcnt(8)" ::: "memory");
            } else if (kk == 7 && jc == 3) {
                asm volatile("s_waitcnt vmcnt(0)" ::: "memory");
            } else {
                asm volatile("s_waitcnt vmcnt(4)" ::: "memory");
            }
            __builtin_amdgcn_s_barrier();     // buf[cur] staged for all waves
            __builtin_amdgcn_sched_barrier(0);

            __builtin_amdgcn_s_setprio(1);
#pragma unroll
            for (int ni = 0; ni < 8; ni++) {
                int so = (ni * 16 + l16) * 32 + qx * 8;
                bf16x8 hfh = *(const bf16x8*)(&Hsh[cur][so]);
                bf16x8 hfl = *(const bf16x8*)(&Hsl[cur][so]);
                sacc[ni] = __builtin_amdgcn_mfma_f32_16x16x32_bf16(qfh[kk], hfh, sacc[ni], 0, 0, 0);
                sacc[ni] = __builtin_amdgcn_mfma_f32_16x16x32_bf16(qfh[kk], hfl, sacc[ni], 0, 0, 0);
                sacc[ni] = __builtin_amdgcn_mfma_f32_16x16x32_bf16(qfl[kk], hfh, sacc[ni], 0, 0, 0);
            }
            __builtin_amdgcn_s_setprio(0);

            if (kk == 7) {
                // ---- epilogue for this jc: mask + leaky relu + online softmax ----
                u64 am[4][2];
#pragma unroll
                for (int r = 0; r < 4; r++) {
                    am[r][0] = amb[(long)(quad * 4 + r) * (NN / 64) + jc * 2 + 0];
                    am[r][1] = amb[(long)(quad * 4 + r) * (NN / 64) + jc * 2 + 1];
                }
#pragma unroll
                for (int ni = 0; ni < 8; ni++)
#pragma unroll
                    for (int r = 0; r < 4; r++) {
                        float v = sacc[ni][r] + ay_[r];
                        v = v > 0.f ? v : ALPHA_ * v;
                        int bit = (int)((am[r][ni >> 2] >> ((ni * 16 + l16) & 63)) & 1);
                        sacc[ni][r] = bit ? v : NEGV;
                    }
#pragma unroll
                for (int r = 0; r < 4; r++) {
                    float mc = -3.0e38f;
#pragma unroll
                    for (int ni = 0; ni < 8; ni++) mc = fmaxf(mc, sacc[ni][r]);
                    for (int off = 8; off; off >>= 1) mc = fmaxf(mc, __shfl_xor(mc, off));
                    float mnew = fmaxf(m_[r], mc);
                    float scale = __expf(m_[r] - mnew);
                    float ps = 0.f;
#pragma unroll
                    for (int ni = 0; ni < 8; ni++) {
                        float p = __expf(sacc[ni][r] - mnew);
                        sacc[ni][r] = p;
                        ps += p;
                    }
                    for (int off = 8; off; off >>= 1) ps += __shfl_xor(ps, off);
                    l_[r] = l_[r] * scale + ps;
                    m_[r] = mnew;
                    if (l16 == 0)
                        mpm[(((long)b * 4 + jz) * 4 + jc) * NN + i0 + quad * 4 + r] = mnew;
                }
                // ---- P~ store via swizzled per-wave LDS half-tiles (2 rounds) ----
#pragma unroll
                for (int h = 0; h < 2; h++) {
#pragma unroll
                    for (int ni = 0; ni < 4; ni++)
#pragma unroll
                        for (int r = 0; r < 4; r++) {
                            int row = quad * 4 + r;
                            int byt = (row * 128 + (ni * 16 + l16) * 2) ^ ((row & 7) << 4);
                            *(bf16*)((char*)pw + byt) = f2bf(sacc[h * 4 + ni][r]);
                        }
#pragma unroll
                    for (int s2 = 0; s2 < 2; s2++) {
                        int cq = quad + s2 * 4;
                        int byt = (l16 * 128 + cq * 16) ^ ((l16 & 7) << 4);
                        uint4 v = *(const uint4*)((const char*)pw + byt);
                        *(uint4*)(&P[((long)b * NN + i0 + l16) * NN + (long)jz * JW
                                     + jc * 128 + h * 64 + cq * 8]) = v;
                    }
                }
#pragma unroll
                for (int ni = 0; ni < 8; ni++) sacc[ni] = (f32x4){0.f, 0.f, 0.f, 0.f};
            }
            __builtin_amdgcn_sched_barrier(0);
            __builtin_amdgcn_s_barrier();   // all waves done reading buf[cur] before restage
            __builtin_amdgcn_sched_barrier(0);
        }
    }
    if (l16 == 0)
#pragma unroll
        for (int r = 0; r < 4; r++)
            mpl[((long)b * 4 + jz) * NN + i0 + quad * 4 + r] = l_[r];
}

// ---------------- merge window stats -> chunk ratios rs + final scale fin ----------------
// rs[b,c,n] = exp(m_{c-1} - m_c)  (c=1..15; c=0 unused)
// fin[b,n]  = exp(m_15 - m_glob) / l_glob
__global__ void ml_merge(const float* __restrict__ mpm, const float* __restrict__ mpl,
                         float* __restrict__ rs, float* __restrict__ fin) {
    long row = (long)blockIdx.x * blockDim.x + threadIdx.x;  // [0, BB*NN)
    long b = row / NN, n = row % NN;
    float mc[16];
#pragma unroll
    for (int c = 0; c < 16; c++) mc[c] = mpm[(b * 16 + c) * NN + n];
    float m = fmaxf(fmaxf(mc[3], mc[7]), fmaxf(mc[11], mc[15]));
    float l = 0.f;
#pragma unroll
    for (int jz = 0; jz < 4; jz++)
        l += mpl[(b * 4 + jz) * NN + n] * __expf(mc[jz * 4 + 3] - m);
    fin[row] = __expf(mc[15] - m) / l;
#pragma unroll
    for (int c = 1; c < 16; c++)
        rs[(b * 16 + c) * NN + n] = __expf(mc[c - 1] - mc[c]);
}

// ---------------- e = X_bf16[*,512] @ W_f32[5,512]^T (fp32 out) ----------------
__global__ void e_kernel(const bf16* __restrict__ X, const float* __restrict__ Wt,
                         float* __restrict__ out) {
    int lane = threadIdx.x & 63, w = threadIdx.x >> 6;
    long row = (long)blockIdx.x * 4 + w;
    uint4 raw = *(const uint4*)(&X[row * FIN + lane * 8]);
    const bf16* xp = (const bf16*)&raw;
    float xv[8];
    for (int i = 0; i < 8; i++) xv[i] = bf2f(xp[i]);
    for (int e = 0; e < EE; e++) {
        float4 w0 = *(const float4*)(&Wt[e * FIN + lane * 8]);
        float4 w1 = *(const float4*)(&Wt[e * FIN + lane * 8 + 4]);
        float p = xv[0] * w0.x + xv[1] * w0.y + xv[2] * w0.z + xv[3] * w0.w
                + xv[4] * w1.x + xv[5] * w1.y + xv[6] * w1.z + xv[7] * w1.w;
        for (int off = 32; off; off >>= 1) p += __shfl_xor(p, off);
        if (lane == 0) out[row * EE + e] = p;
    }
}

// ---------------- out(fp32) = h1 + h2 + e1.Bw.e2 ----------------
__global__ void final_kernel(float* __restrict__ out,
                             const bf16* __restrict__ h1, const bf16* __restrict__ h2,
                             const float* __restrict__ e1, const float* __restrict__ e2,
                             const float* __restrict__ Bw) {
    long row = blockIdx.x;
    int o = threadIdx.x;
    float a[EE], c[EE];
    for (int i = 0; i < EE; i++) { a[i] = e1[row * EE + i]; c[i] = e2[row * EE + i]; }
    const float* bw = Bw + (long)o * EE * EE;
    float acc = 0.f;
    for (int i = 0; i < EE; i++)
        for (int j = 0; j < EE; j++)
            acc += bw[i * EE + j] * a[i] * c[j];
    long idx = row * FOUT + o;
    out[idx] = acc + bf2f(h1[idx]) + bf2f(h2[idx]);
}

extern "C" void kernel_launch(void* const* d_in, const int* in_sizes, int n_in,
                              void* d_out, int out_size, void* d_ws, size_t ws_size,
                              hipStream_t stream) {
    const float* feat = (const float*)d_in[0];
    const int*   adj  = (const int*)d_in[1];
    const float* W    = (const float*)d_in[2];
    const float* W1   = (const float*)d_in[3];
    const float* W2   = (const float*)d_in[4];
    const float* a1   = (const float*)d_in[5];
    const float* a2   = (const float*)d_in[6];
    const float* a12  = (const float*)d_in[7];
    const float* Lw   = (const float*)d_in[8];
    const float* Rw   = (const float*)d_in[9];
    const float* Bw   = (const float*)d_in[10];
    float* out = (float*)d_out;

    char* ws = (char*)d_ws;
    size_t off = 0;
    auto alloc = [&](size_t bytes) {
        char* p = ws + off;
        off += (bytes + 255) & ~(size_t)255;
        return p;
    };
    bf16* WTh  = (bf16*)alloc((size_t)FOUT * FIN * 2);
    bf16* WTl  = (bf16*)alloc((size_t)FOUT * FIN * 2);
    bf16* W1T  = (bf16*)alloc((size_t)FOUT * FIN * 2);
    bf16* W2T  = (bf16*)alloc((size_t)FOUT * FIN * 2);
    bf16* aTh  = (bf16*)alloc((size_t)FOUT * FOUT * 2);
    bf16* aTl  = (bf16*)alloc((size_t)FOUT * FOUT * 2);
    bf16* fh   = (bf16*)alloc((size_t)BB * NN * FIN * 2);     // 16.8 MB
    bf16* fl   = (bf16*)alloc((size_t)BB * NN * FIN * 2);     // 16.8 MB (fagg later)
    bf16* hh   = (bf16*)alloc((size_t)BB * NN * FOUT * 2);    // 8.4 MB (h1 later)
    bf16* hl   = (bf16*)alloc((size_t)BB * NN * FOUT * 2);    // 8.4 MB (h2 later)
    bf16* featT= (bf16*)alloc((size_t)BB * NN * FIN * 2);     // 16.8 MB
    float* Ay  = (float*)alloc((size_t)BB * NN * 4);
    float* mpm = (float*)alloc((size_t)BB * 4 * 4 * NN * 4);  // 1 MB
    float* mpl = (float*)alloc((size_t)BB * 4 * NN * 4);      // 256 KB
    float* rs  = (float*)alloc((size_t)BB * 16 * NN * 4);     // 2 MB chunk ratios
    float* fin = (float*)alloc((size_t)BB * NN * 4);          // 64 KB final scales
    float* e1  = (float*)alloc((size_t)BB * NN * EE * 4);
    float* e2  = (float*)alloc((size_t)BB * NN * EE * 4);
    u64* adjm  = (u64*)alloc((size_t)BB * NN * (NN / 64) * 8);// 4.2 MB
    bf16* P    = (bf16*)alloc((size_t)BB * NN * NN * 2);      // 67.1 MB (all batches)
    // aliases (lifetimes disjoint):  peak ws ~140 MB (ws is ~512 MB)
    bf16* qh   = (bf16*)d_out;                          // q pair in out (16.8 MB)
    bf16* ql   = qh + (size_t)BB * NN * FOUT;
    bf16* fagg = fl;                                    // fl dead after h-GEMM
    bf16* h1   = hh;                                    // h pair dead after scores
    bf16* h2   = hl;

    dim3 tb(32, 8, 1);
    // input conversions
    split_f32_bf16<<<(BB * NN * FIN) / (256 * 8), 256, 0, stream>>>(feat, fh, fl);
    pack_adj<<<(BB * NN * NN) / (256 * 4), 256, 0, stream>>>(adj, adjm);
    transpose_split<<<dim3(FOUT / 32, FIN / 32, 1), tb, 0, stream>>>(W, WTh, WTl, FIN, FOUT);
    transpose_split<<<dim3(FOUT / 32, FOUT / 32, 1), tb, 0, stream>>>(a12, aTh, aTl, FOUT, FOUT);
    transpose_f32_bf16<<<dim3(FOUT / 32, FIN / 32, 1), tb, 0, stream>>>(W1, W1T, FIN, FOUT, 0, 0);
    transpose_f32_bf16<<<dim3(FOUT / 32, FIN / 32, 1), tb, 0, stream>>>(W2, W2T, FIN, FOUT, 0, 0);
    transpose_f32_bf16<<<dim3(FIN / 32, NN / 32, BB), tb, 0, stream>>>(
        feat, featT, NN, FIN, (long)NN * FIN, (long)FIN * NN);
    // h = feat @ W   (split precision; 64-row tiles -> 512 blocks = 2/CU)
    gemm_bt_split<<<dim3(BB * NN / 64, FOUT / 128, 1), 256, 0, stream>>>(
        fh, fl, WTh, WTl, hh, hl, nullptr, FOUT, FIN);
    // Ay = h @ a2
    ay_kernel<<<BB * NN / 4, 256, 0, stream>>>(hh, hl, a2, Ay);
    // q = h @ a12 + a1   (folds Ax[j] into q.h)
    gemm_bt_split<<<dim3(BB * NN / 64, FOUT / 128, 1), 256, 0, stream>>>(
        hh, hl, aTh, aTl, qh, ql, a1, FOUT, FOUT);
    // attention: scores+P~ -> merge -> fused-rescale PV  (no fixup pass)
    pass_score<<<dim3(NN / 64, 4, BB), 256, 0, stream>>>(
        qh, ql, hh, hl, adjm, Ay, mpm, mpl, P);
    ml_merge<<<(BB * NN) / 256, 256, 0, stream>>>(mpm, mpl, rs, fin);
    gemm_pv<<<dim3(512, 1, 1), 256, 0, stream>>>(
        P, featT, fagg, rs, fin);
    // h1 = feat @ W1 ; h2 = fagg @ W2   (64-row tiles)
    gemm_bt<<<dim3(BB * NN / 64, FOUT / 128, 1), 256, 0, stream>>>(
        fh, W1T, h1, FOUT, FIN, 0, 0, 0);
    gemm_bt<<<dim3(BB * NN / 64, FOUT / 128, 1), 256, 0, stream>>>(
        fagg, W2T, h2, FOUT, FIN, 0, 0, 0);
    // e1 = feat @ Lw^T ; e2 = fagg @ Rw^T
    e_kernel<<<BB * NN / 4, 256, 0, stream>>>(fh, Lw, e1);
    e_kernel<<<BB * NN / 4, 256, 0, stream>>>(fagg, Rw, e2);
    // out = h1 + h2 + e1.Bw.e2
    final_kernel<<<BB * NN, FOUT, 0, stream>>>(out, h1, h2, e1, e2, Bw);
}